// Round 3
// baseline (387.880 us; speedup 1.0000x reference)
//
#include <hip/hip_runtime.h>
#include <hip/hip_bf16.h>
#include <math.h>

#define Bb   64
#define Nn   256
#define Mm   16
#define ONF  92
#define OEF  41
#define NF   128
#define EF   64
#define KDIM 320   // 2*NF + EF
#define ODIM 256   // 2*NF
#define FINAL 128
#define K0C  6     // fallback conv K-chunks

#define LOG2E_F 1.44269504088896f
#define LN2_F   0.6931471805599453f

typedef __attribute__((ext_vector_type(8))) short short8;
typedef __attribute__((ext_vector_type(4))) float f32x4;
typedef unsigned int uint;
typedef unsigned short ushort;

#define AS1 __attribute__((address_space(1)))
#define AS3 __attribute__((address_space(3)))

__device__ __forceinline__ void gl2lds16(const void* gp, void* lp) {
    __builtin_amdgcn_global_load_lds((AS1 void*)(void*)gp, (AS3 void*)lp, 16, 0, 0);
}
#define KEEP8(x) asm volatile("" : "+v"(x))

__device__ __forceinline__ float sigmoidf_(float x) {
    float e = __expf(-x);
    return __builtin_amdgcn_rcpf(1.0f + e);
}
__device__ __forceinline__ float softplusf_(float x) {
    return fmaxf(x, 0.0f) + __logf(1.0f + __expf(-fabsf(x)));
}
__device__ __forceinline__ __hip_bfloat16 to_bf16(float x) { return __float2bfloat16(x); }
__device__ __forceinline__ float lo16(uint u) { return __uint_as_float(u << 16); }
__device__ __forceinline__ float hi16(uint u) { return __uint_as_float(u & 0xffff0000u); }
__device__ __forceinline__ ushort bfbits(float x) {
    __hip_bfloat16 b = __float2bfloat16(x);
    return *(ushort*)&b;
}

// ---------- mega-prep: all weight swizzles + WeT + DA in ONE launch ----------
__device__ __forceinline__ void swz(const float* __restrict__ in, __hip_bfloat16* __restrict__ out,
                                    int t, int Itot, int koff, int Kuse, int K0, float scale)
{
    int j = t & 7;
    int u = t >> 3;
    int lane = u & 63;
    int ln16 = lane & 15, q = lane >> 4;
    int v = u >> 6;
    int k0 = v % K0, tile = v / K0;
    int n = tile * 16 + ln16, k = k0 * 32 + q * 8 + j;
    out[t] = (k < Kuse) ? to_bf16(scale * in[(size_t)n * Itot + koff + k]) : to_bf16(0.0f);
}

#define SZ_WET (OEF * EF)          // 2624
#define SZ_WB  (16 * K0C * 512)    // 49152
#define SZ_WS  (16 * 4 * 512)      // 32768
#define SZ_WE2 (16 * 2 * 512)      // 16384
#define SZ_WNB ((NF / 16) * 3 * 512)
#define SZ_WEB ((EF / 16) * 2 * 512)
#define SZ_WFB ((64 / 16) * 4 * 512)
#define SZ_DA  (Nn * Nn)
#define PREP_TOTAL (SZ_WET + 3 * SZ_WB + 3 * SZ_WS + SZ_WNB + SZ_WEB + SZ_WFB + 3 * SZ_WS + 3 * SZ_WE2 + SZ_DA)

__global__ __launch_bounds__(256) void k_prep(
    const float* __restrict__ We, const float* __restrict__ W1,
    const float* __restrict__ W2, const float* __restrict__ W3,
    const float* __restrict__ Wn, const float* __restrict__ Wf,
    const float* __restrict__ dis, const float* __restrict__ pw, const float* __restrict__ pb,
    float* __restrict__ WeT,
    __hip_bfloat16* __restrict__ W1b, __hip_bfloat16* __restrict__ W2b, __hip_bfloat16* __restrict__ W3b,
    __hip_bfloat16* __restrict__ W1s, __hip_bfloat16* __restrict__ W2s, __hip_bfloat16* __restrict__ W3s,
    __hip_bfloat16* __restrict__ Wnb, __hip_bfloat16* __restrict__ Web, __hip_bfloat16* __restrict__ Wfb,
    __hip_bfloat16* __restrict__ W1g, __hip_bfloat16* __restrict__ W2g, __hip_bfloat16* __restrict__ W3g,
    __hip_bfloat16* __restrict__ W1e2, __hip_bfloat16* __restrict__ W2e2, __hip_bfloat16* __restrict__ W3e2,
    __hip_bfloat16* __restrict__ DAf)
{
    int t = blockIdx.x * 256 + threadIdx.x;
    if (t < SZ_WET) {
        int o = t / OEF, i = t - o * OEF;
        WeT[i * EF + o] = We[t];
        return;
    }
    t -= SZ_WET;
    if (t < SZ_WB) { swz(W1, W1b, t, KDIM, NF, 192, K0C, LOG2E_F); return; }
    t -= SZ_WB;
    if (t < SZ_WB) { swz(W2, W2b, t, KDIM, NF, 192, K0C, LOG2E_F); return; }
    t -= SZ_WB;
    if (t < SZ_WB) { swz(W3, W3b, t, KDIM, NF, 192, K0C, LOG2E_F); return; }
    t -= SZ_WB;
    if (t < SZ_WS) { swz(W1, W1s, t, KDIM, 0, NF, 4, LOG2E_F); return; }
    t -= SZ_WS;
    if (t < SZ_WS) { swz(W2, W2s, t, KDIM, 0, NF, 4, LOG2E_F); return; }
    t -= SZ_WS;
    if (t < SZ_WS) { swz(W3, W3s, t, KDIM, 0, NF, 4, LOG2E_F); return; }
    t -= SZ_WS;
    if (t < SZ_WNB) { swz(Wn, Wnb, t, ONF, 0, ONF, 3, 1.0f); return; }
    t -= SZ_WNB;
    if (t < SZ_WEB) { swz(We, Web, t, OEF, 0, OEF, 2, 1.0f); return; }
    t -= SZ_WEB;
    if (t < SZ_WFB) { swz(Wf, Wfb, t, NF, 0, NF, 4, 1.0f); return; }
    t -= SZ_WFB;
    // gather-half B-frags for the P GEMM (K=128, 16 tiles, K0=4)
    if (t < SZ_WS) { swz(W1, W1g, t, KDIM, NF, NF, 4, LOG2E_F); return; }
    t -= SZ_WS;
    if (t < SZ_WS) { swz(W2, W2g, t, KDIM, NF, NF, 4, LOG2E_F); return; }
    t -= SZ_WS;
    if (t < SZ_WS) { swz(W3, W3g, t, KDIM, NF, NF, 4, LOG2E_F); return; }
    t -= SZ_WS;
    // edge-only frags for the new conv (K=64, 16 tiles, K0=2)
    if (t < SZ_WE2) { swz(W1, W1e2, t, KDIM, 2 * NF, EF, 2, LOG2E_F); return; }
    t -= SZ_WE2;
    if (t < SZ_WE2) { swz(W2, W2e2, t, KDIM, 2 * NF, EF, 2, LOG2E_F); return; }
    t -= SZ_WE2;
    if (t < SZ_WE2) { swz(W3, W3e2, t, KDIM, 2 * NF, EF, 2, LOG2E_F); return; }
    t -= SZ_WE2;
    if (t < SZ_DA) {
        int i = t >> 8, jx = t & 255;
        float v = sigmoidf_(fmaf(*pw, dis[t], *pb));
        int itile = i >> 4, ln16 = i & 15;
        int k0 = jx >> 5, q = (jx >> 3) & 3, jj = jx & 7;
        DAf[(size_t)((((itile * 8 + k0) << 6) + (q << 4) + ln16)) * 8 + jj] = to_bf16(v);
    }
}

// ---------- generic MFMA embed body ----------
template<int KIN, int K0, int NCOLS>
__device__ __forceinline__ void emb_body(
    int bid, const float* __restrict__ X, const __hip_bfloat16* __restrict__ Bswz,
    const float* __restrict__ bias, __hip_bfloat16* __restrict__ Y,
    __hip_bfloat16* A_s, __hip_bfloat16* O_s)
{
    constexpr int KP = K0 * 32;
    constexpr int TPW = NCOLS / 64;
    constexpr int OLD = NCOLS + 24;

    const int row0 = bid * 64;
    const int t = threadIdx.x;

    {
        const float4* Xb = (const float4*)(X + (size_t)row0 * KIN);
        constexpr int NV = (64 * KIN) / 4;
        for (int c = t; c < NV; c += 256) {
            float4 v = Xb[c];
            int flat = c * 4;
            #pragma unroll
            for (int e = 0; e < 4; e++) {
                int f = flat + e;
                int row = f / KIN, k = f - row * KIN;
                int mt = row >> 4, ln16 = row & 15;
                int k0 = k >> 5, q = (k >> 3) & 3, j = k & 7;
                float vv = (e == 0) ? v.x : (e == 1) ? v.y : (e == 2) ? v.z : v.w;
                A_s[(((mt * K0 + k0) << 6) + (q << 4) + ln16) * 8 + j] = to_bf16(vv);
            }
        }
        constexpr int PAD = KP - KIN;
        for (int c = t; c < 64 * PAD; c += 256) {
            int row = c / PAD, k = KIN + (c - row * PAD);
            int mt = row >> 4, ln16 = row & 15;
            int k0 = k >> 5, q = (k >> 3) & 3, j = k & 7;
            A_s[(((mt * K0 + k0) << 6) + (q << 4) + ln16) * 8 + j] = to_bf16(0.0f);
        }
    }
    __syncthreads();

    const int wv = t >> 6, lane = t & 63;
    const int q = lane >> 4, ln16 = lane & 15;

    f32x4 acc[4][TPW];
    #pragma unroll
    for (int p = 0; p < TPW; p++) {
        float bv = bias[(wv * TPW + p) * 16 + ln16];
        #pragma unroll
        for (int mt = 0; mt < 4; mt++) acc[mt][p] = (f32x4){bv, bv, bv, bv};
    }

    short8 bw[TPW][K0];
    #pragma unroll
    for (int p = 0; p < TPW; p++)
        #pragma unroll
        for (int k0 = 0; k0 < K0; k0++)
            bw[p][k0] = *(const short8*)(Bswz + ((size_t)((wv * TPW + p) * K0 + k0) << 9) + (lane << 3));

    #pragma unroll
    for (int k0 = 0; k0 < K0; k0++) {
        short8 af[4];
        #pragma unroll
        for (int mt = 0; mt < 4; mt++)
            af[mt] = *(const short8*)(A_s + (((mt * K0 + k0) << 6) + lane) * 8);
        #pragma unroll
        for (int mt = 0; mt < 4; mt++)
            #pragma unroll
            for (int p = 0; p < TPW; p++)
                acc[mt][p] = __builtin_amdgcn_mfma_f32_16x16x32_bf16(af[mt], bw[p][k0], acc[mt][p], 0, 0, 0);
    }

    #pragma unroll
    for (int mt = 0; mt < 4; mt++)
        #pragma unroll
        for (int p = 0; p < TPW; p++) {
            int col = (wv * TPW + p) * 16 + ln16;
            #pragma unroll
            for (int r = 0; r < 4; r++)
                O_s[(mt * 16 + q * 4 + r) * OLD + col] = to_bf16(acc[mt][p][r]);
        }
    __syncthreads();
    constexpr int CH = NCOLS / 8;
    for (int c = t; c < 64 * CH; c += 256) {
        int row = c / CH, ch = c - row * CH;
        *(uint4*)(Y + (size_t)(row0 + row) * NCOLS + ch * 8) =
            *(const uint4*)(O_s + row * OLD + ch * 8);
    }
}

// blocks [0,256): node embed; [256, 256+4096): edge embed
__global__ __launch_bounds__(256) void k_embed_all(
    const float* __restrict__ node_fea, const __hip_bfloat16* __restrict__ Wnb,
    const float* __restrict__ bn, __hip_bfloat16* __restrict__ nf0,
    const float* __restrict__ edge_fea, const __hip_bfloat16* __restrict__ Web,
    const float* __restrict__ be, __hip_bfloat16* __restrict__ efb)
{
    __shared__ __align__(16) __hip_bfloat16 A_s[4 * 3 * 512];
    __shared__ __align__(16) __hip_bfloat16 O_s[64 * (NF + 24)];
    if (blockIdx.x < 256)
        emb_body<ONF, 3, NF>(blockIdx.x, node_fea, Wnb, bn, nf0, A_s, O_s);
    else
        emb_body<OEF, 2, EF>(blockIdx.x - 256, edge_fea, Web, be, efb, A_s, O_s);
}

// ---------- P GEMM: P[n] = [ log2e*(nf@Wself^T)+log2e*bias | log2e*(nf@Wgath^T) ] ----------
// [16384 x 128] @ [128 x 512] -> bf16 [16384][512]. 32 rows/block, grid 512.
__global__ __launch_bounds__(256) void k_gemm_p(
    const __hip_bfloat16* __restrict__ nf,   // [B*N][128]
    const __hip_bfloat16* __restrict__ Ws,   // self-half B-frag [16][4][512], log2e-scaled
    const __hip_bfloat16* __restrict__ Wg,   // gather-half B-frag [16][4][512], log2e-scaled
    const float* __restrict__ bias,          // [256] raw
    __hip_bfloat16* __restrict__ P)          // [B*N][512]
{
    __shared__ __align__(16) __hip_bfloat16 A_s[8 * 512];
    const int row0 = blockIdx.x * 32;
    const int t = threadIdx.x;
    const int wv = t >> 6, lane = t & 63;
    const int q = lane >> 4, ln16 = lane & 15;

    #pragma unroll
    for (int cc = 0; cc < 2; cc++) {
        int c = 2 * wv + cc;            // chunk = mt*4 + k0
        int mt = c >> 2, k0 = c & 3;
        gl2lds16(nf + (size_t)(row0 + mt * 16 + ln16) * NF + k0 * 32 + q * 8,
                 (char*)A_s + (size_t)(c * 64 + lane) * 16);
    }
    __syncthreads();

    const __hip_bfloat16* wbase = (wv < 2) ? Ws : Wg;
    f32x4 acc[2][8];
    #pragma unroll
    for (int p = 0; p < 8; p++) {
        float bv = (wv < 2) ? bias[(wv * 8 + p) * 16 + ln16] * LOG2E_F : 0.0f;
        acc[0][p] = (f32x4){bv, bv, bv, bv};
        acc[1][p] = (f32x4){bv, bv, bv, bv};
    }

    #pragma unroll
    for (int k0 = 0; k0 < 4; k0++) {
        short8 af0 = *(const short8*)(A_s + ((0 * 4 + k0) * 64 + lane) * 8);
        short8 af1 = *(const short8*)(A_s + ((1 * 4 + k0) * 64 + lane) * 8);
        #pragma unroll
        for (int p = 0; p < 8; p++) {
            int tt = (wv & 1) * 8 + p;
            short8 bw = *(const short8*)(wbase + ((size_t)(tt * 4 + k0) << 9) + (lane << 3));
            acc[0][p] = __builtin_amdgcn_mfma_f32_16x16x32_bf16(af0, bw, acc[0][p], 0, 0, 0);
            acc[1][p] = __builtin_amdgcn_mfma_f32_16x16x32_bf16(af1, bw, acc[1][p], 0, 0, 0);
        }
    }

    #pragma unroll
    for (int mt = 0; mt < 2; mt++)
        #pragma unroll
        for (int p = 0; p < 8; p++) {
            int col = (wv * 8 + p) * 16 + ln16;
            #pragma unroll
            for (int r = 0; r < 4; r++)
                P[(size_t)(row0 + mt * 16 + q * 4 + r) * 512 + col] = to_bf16(acc[mt][p][r]);
        }
}

// ---------- conv layer via hoisted P ----------
// Per block: 16 nodes (4 groups of 4). Per group: EdgeG^T = Wedge(A) x ef^T(B) via
// MFMA (K=64), packed bf16 pairs -> LDS [64 edges][516B rows], then per-node
// epilogue: wave wv owns node g*4+wv, lane owns output cols {2l, 2l+1}; the m-sum
// is a serial 16-iter register accumulation (no cross-lane ops); P[idx] gathered
// as coalesced 4B reads from L2.
__global__ __launch_bounds__(256, 3) void k_conv_p(
    const __hip_bfloat16* __restrict__ nf_in,   // [B*N][128]
    const __hip_bfloat16* __restrict__ efb,     // [B*N*M][64]
    const int*   __restrict__ eidx,             // [B*N][16]
    const __hip_bfloat16* __restrict__ P,       // [B*N][512]: [0:256]=self+bias, [256:512]=gather
    const __hip_bfloat16* __restrict__ Wedge,   // [16][2][512] frag, log2e-scaled
    const float* __restrict__ palpha,
    __hip_bfloat16* __restrict__ nf_out)        // [B*N][128]
{
    __shared__ uint EG[64 * 129];               // 33024 B; row stride 129 words (516B)
    const int node0_blk = blockIdx.x * 16;
    const int bbase = node0_blk & ~255;
    const int t = threadIdx.x;
    const int wv = t >> 6, lane = t & 63;
    const int q = lane >> 4, ln16 = lane & 15;
    const float alpha = *palpha;

    // per-wave weight A-frags: c -> o-tile {2wv, 2wv+1, 8+2wv, 9+2wv} (F,F,C,C)
    short8 ws[4][2];
    #pragma unroll
    for (int c = 0; c < 4; c++) {
        int ct = ((c >> 1) << 3) + 2 * wv + (c & 1);
        #pragma unroll
        for (int k0 = 0; k0 < 2; k0++)
            ws[c][k0] = *(const short8*)(Wedge + ((size_t)(ct * 2 + k0) << 9) + (lane << 3));
    }
    #pragma unroll
    for (int c = 0; c < 4; c++) { KEEP8(ws[c][0]); KEEP8(ws[c][1]); }

    for (int g = 0; g < 4; g++) {
        const int node0g = node0_blk + g * 4;

        // ---- MFMA phase: EdgeG^T, A = weights (rows=outputs), B = ef (cols=edges)
        short8 bfr[4][2];
        #pragma unroll
        for (int et = 0; et < 4; et++)
            #pragma unroll
            for (int k0 = 0; k0 < 2; k0++)
                bfr[et][k0] = *(const short8*)(
                    efb + (size_t)((node0g + et) * 16 + ln16) * EF + k0 * 32 + q * 8);

        f32x4 acc[4][4];   // [et][c]
        #pragma unroll
        for (int et = 0; et < 4; et++)
            #pragma unroll
            for (int c = 0; c < 4; c++) acc[et][c] = (f32x4){0.f, 0.f, 0.f, 0.f};

        #pragma unroll
        for (int k0 = 0; k0 < 2; k0++)
            #pragma unroll
            for (int et = 0; et < 4; et++)
                #pragma unroll
                for (int c = 0; c < 4; c++)
                    acc[et][c] = __builtin_amdgcn_mfma_f32_16x16x32_bf16(
                        ws[c][k0], bfr[et][k0], acc[et][c], 0, 0, 0);

        // pack pairs (r,r+1) -> one u32 (lo = even o), write to EG[e][o/2]
        #pragma unroll
        for (int et = 0; et < 4; et++) {
            const int e = et * 16 + ln16;
            #pragma unroll
            for (int c = 0; c < 4; c++) {
                int ct = ((c >> 1) << 3) + 2 * wv + (c & 1);
                int wbase0 = e * 129 + ct * 8 + q * 2;
                uint u0 = (uint)bfbits(acc[et][c][0]) | ((uint)bfbits(acc[et][c][1]) << 16);
                uint u1 = (uint)bfbits(acc[et][c][2]) | ((uint)bfbits(acc[et][c][3]) << 16);
                EG[wbase0] = u0;
                EG[wbase0 + 1] = u1;
            }
        }
        __syncthreads();

        // ---- epilogue: wave wv <-> node node0g+wv; lane owns cols {2l, 2l+1}
        {
            const int n = node0g + wv;
            const uint* EGrow = EG + (wv * 16) * 129 + lane;
            uint psF = *(const uint*)(P + (size_t)n * 512 + 2 * lane);
            uint psC = *(const uint*)(P + (size_t)n * 512 + 128 + 2 * lane);
            uint sfv = *(const uint*)(nf_in + (size_t)n * NF + 2 * lane);
            float psFlo = lo16(psF), psFhi = hi16(psF);
            float psClo = lo16(psC), psChi = hi16(psC);
            float plo = 0.0f, phi = 0.0f;
            const int4* ip = (const int4*)(eidx + n * Mm);
            #pragma unroll
            for (int mm = 0; mm < 4; mm++) {
                int4 iv = ip[mm];
                #pragma unroll
                for (int k = 0; k < 4; k++) {
                    int im = (k == 0) ? iv.x : (k == 1) ? iv.y : (k == 2) ? iv.z : iv.w;
                    int m = mm * 4 + k;
                    bool msk = im >= 0;
                    int jm = msk ? im : 0;
                    const __hip_bfloat16* pg = P + (size_t)(bbase + jm) * 512 + 256;
                    uint pgF = *(const uint*)(pg + 2 * lane);
                    uint pgC = *(const uint*)(pg + 128 + 2 * lane);
                    uint egF = EGrow[m * 129];
                    uint egC = EGrow[m * 129 + 64];
                    float flo = lo16(egF) + lo16(pgF) + psFlo;
                    float fhi = hi16(egF) + hi16(pgF) + psFhi;
                    float clo = lo16(egC) + lo16(pgC) + psClo;
                    float chi = hi16(egC) + hi16(pgC) + psChi;
                    float slo = __builtin_amdgcn_rcpf(1.0f + __builtin_amdgcn_exp2f(-flo));
                    float shi = __builtin_amdgcn_rcpf(1.0f + __builtin_amdgcn_exp2f(-fhi));
                    float splo = fmaxf(clo, 0.0f) +
                                 __builtin_amdgcn_logf(1.0f + __builtin_amdgcn_exp2f(-fabsf(clo)));
                    float sphi = fmaxf(chi, 0.0f) +
                                 __builtin_amdgcn_logf(1.0f + __builtin_amdgcn_exp2f(-fabsf(chi)));
                    plo += msk ? slo * splo : 0.0f;
                    phi += msk ? shi * sphi : 0.0f;
                }
            }
            float outlo = softplusf_(fmaf(alpha, lo16(sfv), LN2_F * plo));
            float outhi = softplusf_(fmaf(alpha, hi16(sfv), LN2_F * phi));
            uint up = (uint)bfbits(outlo) | ((uint)bfbits(outhi) << 16);
            *(uint*)(nf_out + (size_t)n * NF + 2 * lane) = up;
        }
        __syncthreads();
    }
}

// ---------- fallback conv layer (non-precomp path; unchanged) ----------
template<bool PRECOMP>
__global__ __launch_bounds__(256, 3) void k_conv_mfma(
    const __hip_bfloat16* __restrict__ nf_in,
    const float* __restrict__ edge_fea,
    const __hip_bfloat16* __restrict__ ef_bf,
    const int*   __restrict__ eidx,
    const float* __restrict__ WeT,
    const float* __restrict__ be,
    const __hip_bfloat16* __restrict__ Wb,
    const __hip_bfloat16* __restrict__ Wsb,
    const float* __restrict__ bias,
    const float* __restrict__ palpha,
    __hip_bfloat16* __restrict__ nf_out)
{
    __shared__ __align__(16) __hip_bfloat16 A_s[4 * K0C * 512];
    __shared__ __align__(16) __hip_bfloat16 A_sf[4 * 512];

    const int node0 = blockIdx.x * 4;
    const int b = node0 >> 8;
    const int t = threadIdx.x;
    const int wv = t >> 6, lane = t & 63;
    const int q = lane >> 4, ln16 = lane & 15;
    const int row = (wv << 4) + ln16;

    const int myidx = eidx[node0 * Mm + row];
    const unsigned long long mball = __ballot(eidx[node0 * Mm + lane] >= 0);

    float selfv[8];
    #pragma unroll
    for (int mt = 0; mt < 4; mt++)
        #pragma unroll
        for (int p = 0; p < 2; p++)
            selfv[mt * 2 + p] =
                __bfloat162float(nf_in[(size_t)(node0 + mt) * NF + (2 * wv + p) * 16 + ln16]);

    {
        int j = myidx < 0 ? 0 : myidx;
        const __hip_bfloat16* gathp = nf_in + (size_t)((b << 8) + j) * NF;
        #pragma unroll
        for (int k0 = 0; k0 < 4; k0++)
            *(uint4*)(A_s + ((wv * K0C + k0) * 64 + lane) * 8) =
                *(const uint4*)(gathp + k0 * 32 + q * 8);
        *(uint4*)(A_sf + (wv * 64 + lane) * 8) =
            *(const uint4*)(nf_in + (size_t)(node0 + (ln16 & 3)) * NF + wv * 32 + q * 8);
        if (PRECOMP) {
            const __hip_bfloat16* efp = ef_bf + (size_t)((node0 << 4) + row) * EF;
            #pragma unroll
            for (int k0 = 0; k0 < 2; k0++)
                *(uint4*)(A_s + ((wv * K0C + 4 + k0) * 64 + lane) * 8) =
                    *(const uint4*)(efp + k0 * 32 + q * 8);
        } else {
            for (int c = t; c < 64 * EF; c += 256) {
                int rr = c >> 6, col = c & 63;
                float a = be[col];
                const float* er = edge_fea + (size_t)(node0 * Mm + rr) * OEF;
                #pragma unroll
                for (int i = 0; i < OEF; i++) a = fmaf(er[i], WeT[i * EF + col], a);
                int mt = rr >> 4, l16 = rr & 15;
                int k0 = 4 + (col >> 5), qq = (col >> 3) & 3, jj = col & 7;
                A_s[((mt * K0C + k0) * 64 + qq * 16 + l16) * 8 + jj] = to_bf16(a);
            }
        }
    }
    __syncthreads();

    f32x4 sv[4];
    #pragma unroll
    for (int c = 0; c < 4; c++) {
        int tile = 2 * wv + (c & 1) + ((c >> 1) << 3);
        float bv = bias[tile * 16 + ln16] * LOG2E_F;
        sv[c] = (f32x4){bv, bv, bv, bv};
    }
    #pragma unroll
    for (int k0 = 0; k0 < 4; k0++) {
        short8 afs = *(const short8*)(A_sf + (k0 * 64 + lane) * 8);
        #pragma unroll
        for (int c = 0; c < 4; c++) {
            int tile = 2 * wv + (c & 1) + ((c >> 1) << 3);
            short8 bws = *(const short8*)(Wsb + ((size_t)(tile * 4 + k0) << 9) + (lane << 3));
            sv[c] = __builtin_amdgcn_mfma_f32_16x16x32_bf16(afs, bws, sv[c], 0, 0, 0);
        }
    }

    f32x4 accF[4][2], accC[4][2];
    #pragma unroll
    for (int mt = 0; mt < 4; mt++) {
        #pragma unroll
        for (int p = 0; p < 2; p++) {
            float vF = __shfl(sv[p][mt], ln16);
            float vC = __shfl(sv[2 + p][mt], ln16);
            accF[mt][p] = (f32x4){vF, vF, vF, vF};
            accC[mt][p] = (f32x4){vC, vC, vC, vC};
        }
    }

    const __hip_bfloat16* WF0 = Wb + ((size_t)(2 * wv) * (K0C * 512)) + (lane << 3);
    const __hip_bfloat16* WF1 = WF0 + K0C * 512;
    const __hip_bfloat16* WC0 = WF0 + 8 * (K0C * 512);
    const __hip_bfloat16* WC1 = WC0 + K0C * 512;

    #pragma unroll
    for (int k0 = 0; k0 < K0C; k0++) {
        short8 cF0 = *(const short8*)(WF0 + k0 * 512);
        short8 cF1 = *(const short8*)(WF1 + k0 * 512);
        short8 cC0 = *(const short8*)(WC0 + k0 * 512);
        short8 cC1 = *(const short8*)(WC1 + k0 * 512);
        short8 af[4];
        #pragma unroll
        for (int mt = 0; mt < 4; mt++)
            af[mt] = *(const short8*)(A_s + ((mt * K0C + k0) * 64 + lane) * 8);
        #pragma unroll
        for (int mt = 0; mt < 4; mt++) {
            accF[mt][0] = __builtin_amdgcn_mfma_f32_16x16x32_bf16(af[mt], cF0, accF[mt][0], 0, 0, 0);
            accF[mt][1] = __builtin_amdgcn_mfma_f32_16x16x32_bf16(af[mt], cF1, accF[mt][1], 0, 0, 0);
            accC[mt][0] = __builtin_amdgcn_mfma_f32_16x16x32_bf16(af[mt], cC0, accC[mt][0], 0, 0, 0);
            accC[mt][1] = __builtin_amdgcn_mfma_f32_16x16x32_bf16(af[mt], cC1, accC[mt][1], 0, 0, 0);
        }
    }

    const float alpha = *palpha;
    #pragma unroll
    for (int mt = 0; mt < 4; mt++) {
        const int gnode = node0 + mt;
        unsigned mbits = (unsigned)(mball >> (mt * 16 + q * 4)) & 0xFu;
        #pragma unroll
        for (int p = 0; p < 2; p++) {
            float partial = 0.0f;
            #pragma unroll
            for (int r = 0; r < 4; r++) {
                bool msk = (mbits >> r) & 1u;
                float f2 = accF[mt][p][r];
                float c2 = accC[mt][p][r];
                float sig = __builtin_amdgcn_rcpf(1.0f + __builtin_amdgcn_exp2f(-f2));
                float sp2 = fmaxf(c2, 0.0f) +
                            __builtin_amdgcn_logf(1.0f + __builtin_amdgcn_exp2f(-fabsf(c2)));
                partial += msk ? sig * sp2 : 0.0f;
            }
            partial += __shfl_xor(partial, 16);
            partial += __shfl_xor(partial, 32);
            if (q == 0) {
                int col = (2 * wv + p) * 16 + ln16;
                nf_out[(size_t)gnode * NF + col] =
                    to_bf16(softplusf_(fmaf(alpha, selfv[mt * 2 + p], LN2_F * partial)));
            }
        }
    }
}

// ---------- final linear (MFMA): out[:, :, 0:64] = nf3 @ Wf^T + bf ----------
__global__ __launch_bounds__(256) void k_final_mfma(
    const __hip_bfloat16* __restrict__ nf, const __hip_bfloat16* __restrict__ Wfb,
    const float* __restrict__ bfv, float* __restrict__ out,
    __hip_bfloat16* __restrict__ XT)
{
    __shared__ __align__(16) __hip_bfloat16 A_s[16 * 512];
    const int node0 = blockIdx.x * 64;
    const int bloc = node0 >> 8;
    const int t = threadIdx.x;
    const int wv = t >> 6, lane = t & 63;
    const int q = lane >> 4, ln16 = lane & 15;

    const __hip_bfloat16* rowp = nf + (size_t)(node0 + (wv << 4) + ln16) * NF;
    #pragma unroll
    for (int k0 = 0; k0 < 4; k0++)
        *(uint4*)(A_s + ((wv * 4 + k0) * 64 + lane) * 8) =
            *(const uint4*)(rowp + k0 * 32 + q * 8);
    __syncthreads();

    short8 bw[4];
    #pragma unroll
    for (int k0 = 0; k0 < 4; k0++)
        bw[k0] = *(const short8*)(Wfb + ((size_t)(wv * 4 + k0) * 64 + lane) * 8);

    float bv = bfv[wv * 16 + ln16];
    f32x4 acc[4];
    #pragma unroll
    for (int mt = 0; mt < 4; mt++) acc[mt] = (f32x4){bv, bv, bv, bv};

    #pragma unroll
    for (int k0 = 0; k0 < 4; k0++) {
        short8 af[4];
        #pragma unroll
        for (int mt = 0; mt < 4; mt++)
            af[mt] = *(const short8*)(A_s + ((mt * 4 + k0) * 64 + lane) * 8);
        #pragma unroll
        for (int mt = 0; mt < 4; mt++)
            acc[mt] = __builtin_amdgcn_mfma_f32_16x16x32_bf16(af[mt], bw[k0], acc[mt], 0, 0, 0);
    }

    const int col = (wv << 4) + ln16;
    #pragma unroll
    for (int mt = 0; mt < 4; mt++)
        #pragma unroll
        for (int r = 0; r < 4; r++) {
            int row = mt * 16 + q * 4 + r;
            float v = acc[mt][r];
            out[(size_t)(node0 + row) * FINAL + col] = v;
            XT[(size_t)(bloc * 64 + col) * 256 + (node0 & 255) + row] = to_bf16(v);
        }
}

// ---------- node1 (MFMA): out[:, :, 64:128] = DA @ nff per batch ----------
__global__ __launch_bounds__(256) void k_node1_mfma(
    const __hip_bfloat16* __restrict__ DAf,
    const __hip_bfloat16* __restrict__ XT,
    float* __restrict__ out)
{
    __shared__ __align__(16) __hip_bfloat16 B_s[32 * 512];
    const int blk = blockIdx.x;
    const int b = blk >> 2, i0 = (blk & 3) * 64;
    const int t = threadIdx.x;
    const int wv = t >> 6, lane = t & 63;
    const int q = lane >> 4, ln16 = lane & 15;

    const __hip_bfloat16* xrow = XT + (size_t)(b * 64 + (wv << 4) + ln16) * 256;
    #pragma unroll
    for (int k0 = 0; k0 < 8; k0++)
        *(uint4*)(B_s + ((wv * 8 + k0) * 64 + lane) * 8) =
            *(const uint4*)(xrow + k0 * 32 + q * 8);
    __syncthreads();

    f32x4 acc[4];
    #pragma unroll
    for (int mt = 0; mt < 4; mt++) acc[mt] = (f32x4){0.f, 0.f, 0.f, 0.f};

    #pragma unroll
    for (int k0 = 0; k0 < 8; k0++) {
        short8 bfr = *(const short8*)(B_s + ((wv * 8 + k0) * 64 + lane) * 8);
        short8 af[4];
        #pragma unroll
        for (int mt = 0; mt < 4; mt++)
            af[mt] = *(const short8*)(DAf + (size_t)(((i0 >> 4) + mt) * 8 + k0) * 512 + (lane << 3));
        #pragma unroll
        for (int mt = 0; mt < 4; mt++)
            acc[mt] = __builtin_amdgcn_mfma_f32_16x16x32_bf16(af[mt], bfr, acc[mt], 0, 0, 0);
    }

    #pragma unroll
    for (int mt = 0; mt < 4; mt++)
        #pragma unroll
        for (int r = 0; r < 4; r++) {
            int i = i0 + mt * 16 + q * 4 + r;
            out[(size_t)((b << 8) + i) * FINAL + 64 + (wv << 4) + ln16] = acc[mt][r];
        }
}

extern "C" void kernel_launch(void* const* d_in, const int* in_sizes, int n_in,
                              void* d_out, int out_size, void* d_ws, size_t ws_size,
                              hipStream_t stream)
{
    const float* node_fea = (const float*)d_in[0];
    const float* edge_fea = (const float*)d_in[1];
    const int*   eidx     = (const int*)  d_in[2];
    const float* dis      = (const float*)d_in[3];
    const float* Wn = (const float*)d_in[4];
    const float* bn = (const float*)d_in[5];
    const float* We = (const float*)d_in[6];
    const float* be = (const float*)d_in[7];
    const float* W1 = (const float*)d_in[8];
    const float* b1 = (const float*)d_in[9];
    const float* a1 = (const float*)d_in[10];
    const float* W2 = (const float*)d_in[11];
    const float* b2 = (const float*)d_in[12];
    const float* a2 = (const float*)d_in[13];
    const float* W3 = (const float*)d_in[14];
    const float* b3 = (const float*)d_in[15];
    const float* a3 = (const float*)d_in[16];
    const float* Wf = (const float*)d_in[17];
    const float* bf = (const float*)d_in[18];
    const float* DAw = (const float*)d_in[19];
    const float* DAb = (const float*)d_in[20];
    float* out = (float*)d_out;

    // workspace layout (bytes, 256-aligned blocks); fallback-only buffers first,
    // new-path buffers appended at the end.
    char* base = (char*)d_ws;
    size_t off = 0;
    auto alloc = [&](size_t bytes) { char* p = base + off; off = (off + bytes + 255) & ~(size_t)255; return p; };
    __hip_bfloat16* nfA = (__hip_bfloat16*)alloc((size_t)Bb * Nn * NF * 2);
    __hip_bfloat16* nfB = (__hip_bfloat16*)alloc((size_t)Bb * Nn * NF * 2);
    __hip_bfloat16* W1b = (__hip_bfloat16*)alloc((size_t)SZ_WB * 2);
    __hip_bfloat16* W2b = (__hip_bfloat16*)alloc((size_t)SZ_WB * 2);
    __hip_bfloat16* W3b = (__hip_bfloat16*)alloc((size_t)SZ_WB * 2);
    __hip_bfloat16* W1s = (__hip_bfloat16*)alloc((size_t)SZ_WS * 2);
    __hip_bfloat16* W2s = (__hip_bfloat16*)alloc((size_t)SZ_WS * 2);
    __hip_bfloat16* W3s = (__hip_bfloat16*)alloc((size_t)SZ_WS * 2);
    float* WeT = (float*)alloc((size_t)OEF * EF * 4);
    __hip_bfloat16* DAf = (__hip_bfloat16*)alloc((size_t)Nn * Nn * 2);
    __hip_bfloat16* Wnb = (__hip_bfloat16*)alloc((size_t)SZ_WNB * 2);
    __hip_bfloat16* Web = (__hip_bfloat16*)alloc((size_t)SZ_WEB * 2);
    __hip_bfloat16* Wfb = (__hip_bfloat16*)alloc((size_t)SZ_WFB * 2);
    __hip_bfloat16* XT  = (__hip_bfloat16*)alloc((size_t)Bb * 64 * Nn * 2);
    __hip_bfloat16* efb = (__hip_bfloat16*)alloc((size_t)Bb * Nn * Mm * EF * 2);    // 33.5 MB
    __hip_bfloat16* W1g = (__hip_bfloat16*)alloc((size_t)SZ_WS * 2);
    __hip_bfloat16* W2g = (__hip_bfloat16*)alloc((size_t)SZ_WS * 2);
    __hip_bfloat16* W3g = (__hip_bfloat16*)alloc((size_t)SZ_WS * 2);
    __hip_bfloat16* W1e2 = (__hip_bfloat16*)alloc((size_t)SZ_WE2 * 2);
    __hip_bfloat16* W2e2 = (__hip_bfloat16*)alloc((size_t)SZ_WE2 * 2);
    __hip_bfloat16* W3e2 = (__hip_bfloat16*)alloc((size_t)SZ_WE2 * 2);
    __hip_bfloat16* Pbuf = (__hip_bfloat16*)alloc((size_t)Bb * Nn * 512 * 2);       // 16.8 MB
    const bool precomp = (ws_size >= off);

    hipLaunchKernelGGL(k_prep, dim3((PREP_TOTAL + 255) / 256), dim3(256), 0, stream,
                       We, W1, W2, W3, Wn, Wf, dis, DAw, DAb,
                       WeT, W1b, W2b, W3b, W1s, W2s, W3s, Wnb, Web, Wfb,
                       W1g, W2g, W3g, W1e2, W2e2, W3e2, DAf);

    hipLaunchKernelGGL(k_embed_all, dim3(precomp ? (256 + Bb * Nn * Mm / 64) : 256), dim3(256), 0, stream,
                       node_fea, Wnb, bn, nfA, edge_fea, Web, be, efb);

    if (precomp) {
        hipLaunchKernelGGL(k_gemm_p, dim3(Bb * Nn / 32), dim3(256), 0, stream,
                           nfA, W1s, W1g, b1, Pbuf);
        hipLaunchKernelGGL(k_conv_p, dim3(Bb * Nn / 16), dim3(256), 0, stream,
                           nfA, efb, eidx, Pbuf, W1e2, a1, nfB);
        hipLaunchKernelGGL(k_gemm_p, dim3(Bb * Nn / 32), dim3(256), 0, stream,
                           nfB, W2s, W2g, b2, Pbuf);
        hipLaunchKernelGGL(k_conv_p, dim3(Bb * Nn / 16), dim3(256), 0, stream,
                           nfB, efb, eidx, Pbuf, W2e2, a2, nfA);
        hipLaunchKernelGGL(k_gemm_p, dim3(Bb * Nn / 32), dim3(256), 0, stream,
                           nfA, W3s, W3g, b3, Pbuf);
        hipLaunchKernelGGL(k_conv_p, dim3(Bb * Nn / 16), dim3(256), 0, stream,
                           nfA, efb, eidx, Pbuf, W3e2, a3, nfB);
    } else {
        hipLaunchKernelGGL((k_conv_mfma<false>), dim3(Bb * Nn / 4), dim3(256), 0, stream,
                           nfA, edge_fea, efb, eidx, WeT, be, W1b, W1s, b1, a1, nfB);
        hipLaunchKernelGGL((k_conv_mfma<false>), dim3(Bb * Nn / 4), dim3(256), 0, stream,
                           nfB, edge_fea, efb, eidx, WeT, be, W2b, W2s, b2, a2, nfA);
        hipLaunchKernelGGL((k_conv_mfma<false>), dim3(Bb * Nn / 4), dim3(256), 0, stream,
                           nfA, edge_fea, efb, eidx, WeT, be, W3b, W3s, b3, a3, nfB);
    }

    hipLaunchKernelGGL(k_final_mfma, dim3(Bb * Nn / 64), dim3(256), 0, stream, nfB, Wfb, bf, out, XT);
    hipLaunchKernelGGL(k_node1_mfma, dim3(Bb * 4), dim3(256), 0, stream, DAf, XT, out);
}

// Round 4
// 316.757 us; speedup vs baseline: 1.2245x; 1.2245x over previous
//
#include <hip/hip_runtime.h>
#include <hip/hip_bf16.h>
#include <math.h>

#define Bb   64
#define Nn   256
#define Mm   16
#define ONF  92
#define OEF  41
#define NF   128
#define EF   64
#define KDIM 320   // 2*NF + EF
#define ODIM 256   // 2*NF
#define FINAL 128
#define K0C  6     // conv K-chunks (K=192: gather 128 + edge 64)
#define GRP  4     // node-groups (of 4 nodes) per conv block
#define NODESB (4*GRP)

#define LOG2E_F 1.44269504088896f
#define LN2_F   0.6931471805599453f

typedef __attribute__((ext_vector_type(8))) short short8;
typedef __attribute__((ext_vector_type(4))) float f32x4;

#define AS1 __attribute__((address_space(1)))
#define AS3 __attribute__((address_space(3)))

// async global->LDS DMA, 16B per lane. LDS dest must be wave-uniform base + lane*16
// (our fragment layout is exactly that); global source is per-lane. Drained by the
// vmcnt(0) implicit in __syncthreads().
__device__ __forceinline__ void gl2lds16(const void* gp, void* lp) {
    __builtin_amdgcn_global_load_lds((AS1 void*)(void*)gp, (AS3 void*)lp, 16, 0, 0);
}
// pin a 128b value in VGPRs: stops rematerialization/reload inside loops
#define KEEP8(x) asm volatile("" : "+v"(x))

__device__ __forceinline__ float sigmoidf_(float x) {
    float e = __expf(-x);
    return __builtin_amdgcn_rcpf(1.0f + e);
}
__device__ __forceinline__ float softplusf_(float x) {
    return fmaxf(x, 0.0f) + __logf(1.0f + __expf(-fabsf(x)));
}
__device__ __forceinline__ __hip_bfloat16 to_bf16(float x) { return __float2bfloat16(x); }

// ---------- mega-prep: all weight swizzles + WeT + DA in ONE launch ----------
__device__ __forceinline__ void swz(const float* __restrict__ in, __hip_bfloat16* __restrict__ out,
                                    int t, int Itot, int koff, int Kuse, int K0, float scale)
{
    int j = t & 7;
    int u = t >> 3;
    int lane = u & 63;
    int ln16 = lane & 15, q = lane >> 4;
    int v = u >> 6;
    int k0 = v % K0, tile = v / K0;
    int n = tile * 16 + ln16, k = k0 * 32 + q * 8 + j;
    out[t] = (k < Kuse) ? to_bf16(scale * in[(size_t)n * Itot + koff + k]) : to_bf16(0.0f);
}

#define SZ_WET (OEF * EF)          // 2624
#define SZ_WB  (16 * K0C * 512)    // 49152
#define SZ_WS  (16 * 4 * 512)      // 32768
#define SZ_WNB ((NF / 16) * 3 * 512)
#define SZ_WEB ((EF / 16) * 2 * 512)
#define SZ_WFB ((64 / 16) * 4 * 512)
#define SZ_DA  (Nn * Nn)
#define PREP_TOTAL (SZ_WET + 3 * SZ_WB + 3 * SZ_WS + SZ_WNB + SZ_WEB + SZ_WFB + SZ_DA)

__global__ __launch_bounds__(256) void k_prep(
    const float* __restrict__ We, const float* __restrict__ W1,
    const float* __restrict__ W2, const float* __restrict__ W3,
    const float* __restrict__ Wn, const float* __restrict__ Wf,
    const float* __restrict__ dis, const float* __restrict__ pw, const float* __restrict__ pb,
    float* __restrict__ WeT,
    __hip_bfloat16* __restrict__ W1b, __hip_bfloat16* __restrict__ W2b, __hip_bfloat16* __restrict__ W3b,
    __hip_bfloat16* __restrict__ W1s, __hip_bfloat16* __restrict__ W2s, __hip_bfloat16* __restrict__ W3s,
    __hip_bfloat16* __restrict__ Wnb, __hip_bfloat16* __restrict__ Web, __hip_bfloat16* __restrict__ Wfb,
    __hip_bfloat16* __restrict__ DAf)
{
    int t = blockIdx.x * 256 + threadIdx.x;
    if (t < SZ_WET) {
        int o = t / OEF, i = t - o * OEF;
        WeT[i * EF + o] = We[t];
        return;
    }
    t -= SZ_WET;
    if (t < SZ_WB) { swz(W1, W1b, t, KDIM, NF, 192, K0C, LOG2E_F); return; }
    t -= SZ_WB;
    if (t < SZ_WB) { swz(W2, W2b, t, KDIM, NF, 192, K0C, LOG2E_F); return; }
    t -= SZ_WB;
    if (t < SZ_WB) { swz(W3, W3b, t, KDIM, NF, 192, K0C, LOG2E_F); return; }
    t -= SZ_WB;
    if (t < SZ_WS) { swz(W1, W1s, t, KDIM, 0, NF, 4, LOG2E_F); return; }
    t -= SZ_WS;
    if (t < SZ_WS) { swz(W2, W2s, t, KDIM, 0, NF, 4, LOG2E_F); return; }
    t -= SZ_WS;
    if (t < SZ_WS) { swz(W3, W3s, t, KDIM, 0, NF, 4, LOG2E_F); return; }
    t -= SZ_WS;
    if (t < SZ_WNB) { swz(Wn, Wnb, t, ONF, 0, ONF, 3, 1.0f); return; }
    t -= SZ_WNB;
    if (t < SZ_WEB) { swz(We, Web, t, OEF, 0, OEF, 2, 1.0f); return; }
    t -= SZ_WEB;
    if (t < SZ_WFB) { swz(Wf, Wfb, t, NF, 0, NF, 4, 1.0f); return; }
    t -= SZ_WFB;
    if (t < SZ_DA) {
        int i = t >> 8, jx = t & 255;
        float v = sigmoidf_(fmaf(*pw, dis[t], *pb));
        int itile = i >> 4, ln16 = i & 15;
        int k0 = jx >> 5, q = (jx >> 3) & 3, jj = jx & 7;
        DAf[(size_t)((((itile * 8 + k0) << 6) + (q << 4) + ln16)) * 8 + jj] = to_bf16(v);
    }
}

// ---------- generic MFMA embed body ----------
template<int KIN, int K0, int NCOLS>
__device__ __forceinline__ void emb_body(
    int bid, const float* __restrict__ X, const __hip_bfloat16* __restrict__ Bswz,
    const float* __restrict__ bias, __hip_bfloat16* __restrict__ Y,
    __hip_bfloat16* A_s, __hip_bfloat16* O_s)
{
    constexpr int KP = K0 * 32;
    constexpr int TPW = NCOLS / 64;
    constexpr int OLD = NCOLS + 24;

    const int row0 = bid * 64;
    const int t = threadIdx.x;

    {
        const float4* Xb = (const float4*)(X + (size_t)row0 * KIN);
        constexpr int NV = (64 * KIN) / 4;
        for (int c = t; c < NV; c += 256) {
            float4 v = Xb[c];
            int flat = c * 4;
            #pragma unroll
            for (int e = 0; e < 4; e++) {
                int f = flat + e;
                int row = f / KIN, k = f - row * KIN;
                int mt = row >> 4, ln16 = row & 15;
                int k0 = k >> 5, q = (k >> 3) & 3, j = k & 7;
                float vv = (e == 0) ? v.x : (e == 1) ? v.y : (e == 2) ? v.z : v.w;
                A_s[(((mt * K0 + k0) << 6) + (q << 4) + ln16) * 8 + j] = to_bf16(vv);
            }
        }
        constexpr int PAD = KP - KIN;
        for (int c = t; c < 64 * PAD; c += 256) {
            int row = c / PAD, k = KIN + (c - row * PAD);
            int mt = row >> 4, ln16 = row & 15;
            int k0 = k >> 5, q = (k >> 3) & 3, j = k & 7;
            A_s[(((mt * K0 + k0) << 6) + (q << 4) + ln16) * 8 + j] = to_bf16(0.0f);
        }
    }
    __syncthreads();

    const int wv = t >> 6, lane = t & 63;
    const int q = lane >> 4, ln16 = lane & 15;

    f32x4 acc[4][TPW];
    #pragma unroll
    for (int p = 0; p < TPW; p++) {
        float bv = bias[(wv * TPW + p) * 16 + ln16];
        #pragma unroll
        for (int mt = 0; mt < 4; mt++) acc[mt][p] = (f32x4){bv, bv, bv, bv};
    }

    short8 bw[TPW][K0];
    #pragma unroll
    for (int p = 0; p < TPW; p++)
        #pragma unroll
        for (int k0 = 0; k0 < K0; k0++)
            bw[p][k0] = *(const short8*)(Bswz + ((size_t)((wv * TPW + p) * K0 + k0) << 9) + (lane << 3));

    #pragma unroll
    for (int k0 = 0; k0 < K0; k0++) {
        short8 af[4];
        #pragma unroll
        for (int mt = 0; mt < 4; mt++)
            af[mt] = *(const short8*)(A_s + (((mt * K0 + k0) << 6) + lane) * 8);
        #pragma unroll
        for (int mt = 0; mt < 4; mt++)
            #pragma unroll
            for (int p = 0; p < TPW; p++)
                acc[mt][p] = __builtin_amdgcn_mfma_f32_16x16x32_bf16(af[mt], bw[p][k0], acc[mt][p], 0, 0, 0);
    }

    #pragma unroll
    for (int mt = 0; mt < 4; mt++)
        #pragma unroll
        for (int p = 0; p < TPW; p++) {
            int col = (wv * TPW + p) * 16 + ln16;
            #pragma unroll
            for (int r = 0; r < 4; r++)
                O_s[(mt * 16 + q * 4 + r) * OLD + col] = to_bf16(acc[mt][p][r]);
        }
    __syncthreads();
    constexpr int CH = NCOLS / 8;
    for (int c = t; c < 64 * CH; c += 256) {
        int row = c / CH, ch = c - row * CH;
        *(uint4*)(Y + (size_t)(row0 + row) * NCOLS + ch * 8) =
            *(const uint4*)(O_s + row * OLD + ch * 8);
    }
}

// blocks [0,256): node embed; [256, 256+4096): edge embed
__global__ __launch_bounds__(256) void k_embed_all(
    const float* __restrict__ node_fea, const __hip_bfloat16* __restrict__ Wnb,
    const float* __restrict__ bn, __hip_bfloat16* __restrict__ nf0,
    const float* __restrict__ edge_fea, const __hip_bfloat16* __restrict__ Web,
    const float* __restrict__ be, __hip_bfloat16* __restrict__ efb)
{
    __shared__ __align__(16) __hip_bfloat16 A_s[4 * 3 * 512];
    __shared__ __align__(16) __hip_bfloat16 O_s[64 * (NF + 24)];
    if (blockIdx.x < 256)
        emb_body<ONF, 3, NF>(blockIdx.x, node_fea, Wnb, bn, nf0, A_s, O_s);
    else
        emb_body<OEF, 2, EF>(blockIdx.x - 256, edge_fea, Web, be, efb, A_s, O_s);
}

// ---------- blocked conv layer (PRECOMP path) ----------
// R4: 16 nodes (4 groups of 4) per block, grid 1024. Weight fragments loaded once
// per block (pinned); self-phase A-frags read DIRECTLY from global (L2-hot; drops
// the 8KB A_sf, LDS 57.3->49.2KB => 3 blocks/CU resident instead of 2). Self phase
// runs BEFORE the first barrier, overlapping the group-0 DMA drain. A-tile
// double-buffered via global_load_lds, one __syncthreads per group.
__global__ __launch_bounds__(256, 3) void k_conv_blk(
    const __hip_bfloat16* __restrict__ nf_in,   // [B*N][NF] bf16
    const __hip_bfloat16* __restrict__ ef_bf,   // [B*N*M][EF] bf16
    const int*   __restrict__ eidx,             // [B*N][M]
    const __hip_bfloat16* __restrict__ Wb,      // [16][K0C][64][8] (log2e*W[:,128:320])
    const __hip_bfloat16* __restrict__ Wsb,     // [16][4][64][8]   (log2e*W[:,0:128])
    const float* __restrict__ bias,             // [ODIM]
    const float* __restrict__ palpha,
    __hip_bfloat16* __restrict__ nf_out)        // [B*N][NF] bf16
{
    __shared__ __align__(16) __hip_bfloat16 A_s[2][4 * K0C * 512];  // 2 x 24576 B

    const int node0_blk = blockIdx.x * NODESB;       // 16 nodes
    const int bbase = node0_blk & ~255;              // (b<<8)
    const int t = threadIdx.x;
    const int wv = t >> 6, lane = t & 63;
    const int q = lane >> 4, ln16 = lane & 15;
    const int row = (wv << 4) + ln16;                // lane's edge-row within a group
    const float alpha = *palpha;

    // ---- stage helper: gather + edge fragments of group at node0g into buf
    auto stage_group = [&](int node0g, __hip_bfloat16* buf) -> unsigned long long {
        int mi = eidx[node0g * Mm + row];
        unsigned long long mb = __ballot(eidx[node0g * Mm + lane] >= 0);
        int j = mi < 0 ? 0 : mi;
        const __hip_bfloat16* gathp = nf_in + (size_t)(bbase + j) * NF + q * 8;
        #pragma unroll
        for (int k0 = 0; k0 < 4; k0++)
            gl2lds16(gathp + k0 * 32, buf + (wv * K0C + k0) * 512 + lane * 8);
        const __hip_bfloat16* efp = ef_bf + (size_t)((node0g << 4) + row) * EF + q * 8;
        #pragma unroll
        for (int k0 = 0; k0 < 2; k0++)
            gl2lds16(efp + k0 * 32, buf + (wv * K0C + 4 + k0) * 512 + lane * 8);
        return mb;
    };

    // ---- issue group-0 DMA first (latency hidden under weight load + self phase)
    unsigned long long mb_next = stage_group(node0_blk, A_s[0]);

    // ---- main-loop weight preload (once per block; pinned below)
    const __hip_bfloat16* WF0 = Wb + ((size_t)(2 * wv) * (K0C * 512)) + (lane << 3);
    const __hip_bfloat16* WF1 = WF0 + K0C * 512;
    const __hip_bfloat16* WC0 = WF0 + 8 * (K0C * 512);
    const __hip_bfloat16* WC1 = WC0 + K0C * 512;
    short8 mF0[K0C], mF1[K0C], mC0[K0C], mC1[K0C];
    #pragma unroll
    for (int k0 = 0; k0 < K0C; k0++) {
        mF0[k0] = *(const short8*)(WF0 + k0 * 512);
        mF1[k0] = *(const short8*)(WF1 + k0 * 512);
        mC0[k0] = *(const short8*)(WC0 + k0 * 512);
        mC1[k0] = *(const short8*)(WC1 + k0 * 512);
    }

    // ---- self phase for the 16 block rows: A-frags direct from global (L2-hot)
    // lane(q,ln16) reg r of sv[c] = S[row=q*4+r][col=tile(c)*16+ln16]
    f32x4 sv[4];
    #pragma unroll
    for (int c = 0; c < 4; c++) {
        int tile = 2 * wv + (c & 1) + ((c >> 1) << 3);
        float bv = bias[tile * 16 + ln16] * LOG2E_F;
        sv[c] = (f32x4){bv, bv, bv, bv};
    }
    #pragma unroll
    for (int k0 = 0; k0 < 4; k0++) {
        short8 afs = *(const short8*)(nf_in + (size_t)(node0_blk + ln16) * NF + k0 * 32 + q * 8);
        #pragma unroll
        for (int c = 0; c < 4; c++) {
            int tile = 2 * wv + (c & 1) + ((c >> 1) << 3);
            short8 bws = *(const short8*)(Wsb + ((size_t)(tile * 4 + k0) << 9) + (lane << 3));
            sv[c] = __builtin_amdgcn_mfma_f32_16x16x32_bf16(afs, bws, sv[c], 0, 0, 0);
        }
    }

    // pin weight regs (defeats rematerialization inside the group loop)
    #pragma unroll
    for (int k0 = 0; k0 < K0C; k0++) {
        KEEP8(mF0[k0]); KEEP8(mF1[k0]); KEEP8(mC0[k0]); KEEP8(mC1[k0]);
    }

    __syncthreads();   // drains group-0 DMA

    // ---- group loop
    int cur = 0;
    for (int g = 0; g < GRP; g++) {
        const int node0g = node0_blk + g * 4;
        const unsigned long long mb_cur = mb_next;
        if (g + 1 < GRP) mb_next = stage_group(node0g + 4, A_s[cur ^ 1]);

        // epilogue self-read (issued early; L2-hot; used at the very end)
        float selfv[8];
        #pragma unroll
        for (int mt = 0; mt < 4; mt++)
            #pragma unroll
            for (int p = 0; p < 2; p++)
                selfv[mt * 2 + p] =
                    __bfloat162float(nf_in[(size_t)(node0g + mt) * NF + (2 * wv + p) * 16 + ln16]);

        const int srcl = (g << 4) + ln16;
        const __hip_bfloat16* Acur = A_s[cur];

        #pragma unroll
        for (int h = 0; h < 2; h++) {
            // acc init: broadcast S[g*4+mt][col] from self-phase regs
            f32x4 accF[2][2], accC[2][2];
            #pragma unroll
            for (int mtl = 0; mtl < 2; mtl++) {
                const int mt = 2 * h + mtl;
                #pragma unroll
                for (int p = 0; p < 2; p++) {
                    float vF = __shfl(sv[p][mt], srcl);
                    float vC = __shfl(sv[2 + p][mt], srcl);
                    accF[mtl][p] = (f32x4){vF, vF, vF, vF};
                    accC[mtl][p] = (f32x4){vC, vC, vC, vC};
                }
            }
            // K-loop: pure LDS + MFMA, weights in pinned regs
            #pragma unroll
            for (int k0 = 0; k0 < K0C; k0++) {
                short8 af[2];
                #pragma unroll
                for (int mtl = 0; mtl < 2; mtl++)
                    af[mtl] = *(const short8*)(Acur + (((2 * h + mtl) * K0C + k0) * 64 + lane) * 8);
                #pragma unroll
                for (int mtl = 0; mtl < 2; mtl++) {
                    accF[mtl][0] = __builtin_amdgcn_mfma_f32_16x16x32_bf16(af[mtl], mF0[k0], accF[mtl][0], 0, 0, 0);
                    accF[mtl][1] = __builtin_amdgcn_mfma_f32_16x16x32_bf16(af[mtl], mF1[k0], accF[mtl][1], 0, 0, 0);
                    accC[mtl][0] = __builtin_amdgcn_mfma_f32_16x16x32_bf16(af[mtl], mC0[k0], accC[mtl][0], 0, 0, 0);
                    accC[mtl][1] = __builtin_amdgcn_mfma_f32_16x16x32_bf16(af[mtl], mC1[k0], accC[mtl][1], 0, 0, 0);
                }
            }
            // epilogue (log2-domain)
            #pragma unroll
            for (int mtl = 0; mtl < 2; mtl++) {
                const int mt = 2 * h + mtl;
                const int gnode = node0g + mt;
                unsigned mbits = (unsigned)(mb_cur >> (mt * 16 + q * 4)) & 0xFu;
                #pragma unroll
                for (int p = 0; p < 2; p++) {
                    float partial = 0.0f;
                    #pragma unroll
                    for (int r = 0; r < 4; r++) {
                        bool msk = (mbits >> r) & 1u;
                        float f2 = accF[mtl][p][r];
                        float c2 = accC[mtl][p][r];
                        float sig = __builtin_amdgcn_rcpf(1.0f + __builtin_amdgcn_exp2f(-f2));
                        float sp2 = fmaxf(c2, 0.0f) +
                                    __builtin_amdgcn_logf(1.0f + __builtin_amdgcn_exp2f(-fabsf(c2)));
                        partial += msk ? sig * sp2 : 0.0f;
                    }
                    partial += __shfl_xor(partial, 16);
                    partial += __shfl_xor(partial, 32);
                    if (q == 0) {
                        int col = (2 * wv + p) * 16 + ln16;
                        nf_out[(size_t)gnode * NF + col] =
                            to_bf16(softplusf_(fmaf(alpha, selfv[mt * 2 + p], LN2_F * partial)));
                    }
                }
            }
        }
        __syncthreads();   // drains stage(g+1) DMAs; releases A_s[cur] for restaging
        cur ^= 1;
    }
}

// ---------- fallback conv layer (non-precomp path; unchanged) ----------
template<bool PRECOMP>
__global__ __launch_bounds__(256, 3) void k_conv_mfma(
    const __hip_bfloat16* __restrict__ nf_in,
    const float* __restrict__ edge_fea,
    const __hip_bfloat16* __restrict__ ef_bf,
    const int*   __restrict__ eidx,
    const float* __restrict__ WeT,
    const float* __restrict__ be,
    const __hip_bfloat16* __restrict__ Wb,
    const __hip_bfloat16* __restrict__ Wsb,
    const float* __restrict__ bias,
    const float* __restrict__ palpha,
    __hip_bfloat16* __restrict__ nf_out)
{
    __shared__ __align__(16) __hip_bfloat16 A_s[4 * K0C * 512];
    __shared__ __align__(16) __hip_bfloat16 A_sf[4 * 512];

    const int node0 = blockIdx.x * 4;
    const int b = node0 >> 8;
    const int t = threadIdx.x;
    const int wv = t >> 6, lane = t & 63;
    const int q = lane >> 4, ln16 = lane & 15;
    const int row = (wv << 4) + ln16;

    const int myidx = eidx[node0 * Mm + row];
    const unsigned long long mball = __ballot(eidx[node0 * Mm + lane] >= 0);

    float selfv[8];
    #pragma unroll
    for (int mt = 0; mt < 4; mt++)
        #pragma unroll
        for (int p = 0; p < 2; p++)
            selfv[mt * 2 + p] =
                __bfloat162float(nf_in[(size_t)(node0 + mt) * NF + (2 * wv + p) * 16 + ln16]);

    {
        int j = myidx < 0 ? 0 : myidx;
        const __hip_bfloat16* gathp = nf_in + (size_t)((b << 8) + j) * NF;
        #pragma unroll
        for (int k0 = 0; k0 < 4; k0++)
            *(uint4*)(A_s + ((wv * K0C + k0) * 64 + lane) * 8) =
                *(const uint4*)(gathp + k0 * 32 + q * 8);
        *(uint4*)(A_sf + (wv * 64 + lane) * 8) =
            *(const uint4*)(nf_in + (size_t)(node0 + (ln16 & 3)) * NF + wv * 32 + q * 8);
        if (PRECOMP) {
            const __hip_bfloat16* efp = ef_bf + (size_t)((node0 << 4) + row) * EF;
            #pragma unroll
            for (int k0 = 0; k0 < 2; k0++)
                *(uint4*)(A_s + ((wv * K0C + 4 + k0) * 64 + lane) * 8) =
                    *(const uint4*)(efp + k0 * 32 + q * 8);
        } else {
            for (int c = t; c < 64 * EF; c += 256) {
                int rr = c >> 6, col = c & 63;
                float a = be[col];
                const float* er = edge_fea + (size_t)(node0 * Mm + rr) * OEF;
                #pragma unroll
                for (int i = 0; i < OEF; i++) a = fmaf(er[i], WeT[i * EF + col], a);
                int mt = rr >> 4, l16 = rr & 15;
                int k0 = 4 + (col >> 5), qq = (col >> 3) & 3, jj = col & 7;
                A_s[((mt * K0C + k0) * 64 + qq * 16 + l16) * 8 + jj] = to_bf16(a);
            }
        }
    }
    __syncthreads();

    f32x4 sv[4];
    #pragma unroll
    for (int c = 0; c < 4; c++) {
        int tile = 2 * wv + (c & 1) + ((c >> 1) << 3);
        float bv = bias[tile * 16 + ln16] * LOG2E_F;
        sv[c] = (f32x4){bv, bv, bv, bv};
    }
    #pragma unroll
    for (int k0 = 0; k0 < 4; k0++) {
        short8 afs = *(const short8*)(A_sf + (k0 * 64 + lane) * 8);
        #pragma unroll
        for (int c = 0; c < 4; c++) {
            int tile = 2 * wv + (c & 1) + ((c >> 1) << 3);
            short8 bws = *(const short8*)(Wsb + ((size_t)(tile * 4 + k0) << 9) + (lane << 3));
            sv[c] = __builtin_amdgcn_mfma_f32_16x16x32_bf16(afs, bws, sv[c], 0, 0, 0);
        }
    }

    f32x4 accF[4][2], accC[4][2];
    #pragma unroll
    for (int mt = 0; mt < 4; mt++) {
        #pragma unroll
        for (int p = 0; p < 2; p++) {
            float vF = __shfl(sv[p][mt], ln16);
            float vC = __shfl(sv[2 + p][mt], ln16);
            accF[mt][p] = (f32x4){vF, vF, vF, vF};
            accC[mt][p] = (f32x4){vC, vC, vC, vC};
        }
    }

    const __hip_bfloat16* WF0 = Wb + ((size_t)(2 * wv) * (K0C * 512)) + (lane << 3);
    const __hip_bfloat16* WF1 = WF0 + K0C * 512;
    const __hip_bfloat16* WC0 = WF0 + 8 * (K0C * 512);
    const __hip_bfloat16* WC1 = WC0 + K0C * 512;

    #pragma unroll
    for (int k0 = 0; k0 < K0C; k0++) {
        short8 cF0 = *(const short8*)(WF0 + k0 * 512);
        short8 cF1 = *(const short8*)(WF1 + k0 * 512);
        short8 cC0 = *(const short8*)(WC0 + k0 * 512);
        short8 cC1 = *(const short8*)(WC1 + k0 * 512);
        short8 af[4];
        #pragma unroll
        for (int mt = 0; mt < 4; mt++)
            af[mt] = *(const short8*)(A_s + ((mt * K0C + k0) * 64 + lane) * 8);
        #pragma unroll
        for (int mt = 0; mt < 4; mt++) {
            accF[mt][0] = __builtin_amdgcn_mfma_f32_16x16x32_bf16(af[mt], cF0, accF[mt][0], 0, 0, 0);
            accF[mt][1] = __builtin_amdgcn_mfma_f32_16x16x32_bf16(af[mt], cF1, accF[mt][1], 0, 0, 0);
            accC[mt][0] = __builtin_amdgcn_mfma_f32_16x16x32_bf16(af[mt], cC0, accC[mt][0], 0, 0, 0);
            accC[mt][1] = __builtin_amdgcn_mfma_f32_16x16x32_bf16(af[mt], cC1, accC[mt][1], 0, 0, 0);
        }
    }

    const float alpha = *palpha;
    #pragma unroll
    for (int mt = 0; mt < 4; mt++) {
        const int gnode = node0 + mt;
        unsigned mbits = (unsigned)(mball >> (mt * 16 + q * 4)) & 0xFu;
        #pragma unroll
        for (int p = 0; p < 2; p++) {
            float partial = 0.0f;
            #pragma unroll
            for (int r = 0; r < 4; r++) {
                bool msk = (mbits >> r) & 1u;
                float f2 = accF[mt][p][r];
                float c2 = accC[mt][p][r];
                float sig = __builtin_amdgcn_rcpf(1.0f + __builtin_amdgcn_exp2f(-f2));
                float sp2 = fmaxf(c2, 0.0f) +
                            __builtin_amdgcn_logf(1.0f + __builtin_amdgcn_exp2f(-fabsf(c2)));
                partial += msk ? sig * sp2 : 0.0f;
            }
            partial += __shfl_xor(partial, 16);
            partial += __shfl_xor(partial, 32);
            if (q == 0) {
                int col = (2 * wv + p) * 16 + ln16;
                nf_out[(size_t)gnode * NF + col] =
                    to_bf16(softplusf_(fmaf(alpha, selfv[mt * 2 + p], LN2_F * partial)));
            }
        }
    }
}

// ---------- final linear (MFMA): out[:, :, 0:64] = nf3 @ Wf^T + bf ----------
__global__ __launch_bounds__(256) void k_final_mfma(
    const __hip_bfloat16* __restrict__ nf, const __hip_bfloat16* __restrict__ Wfb,
    const float* __restrict__ bfv, float* __restrict__ out,
    __hip_bfloat16* __restrict__ XT)
{
    __shared__ __align__(16) __hip_bfloat16 A_s[16 * 512];
    const int node0 = blockIdx.x * 64;
    const int bloc = node0 >> 8;
    const int t = threadIdx.x;
    const int wv = t >> 6, lane = t & 63;
    const int q = lane >> 4, ln16 = lane & 15;

    const __hip_bfloat16* rowp = nf + (size_t)(node0 + (wv << 4) + ln16) * NF;
    #pragma unroll
    for (int k0 = 0; k0 < 4; k0++)
        *(uint4*)(A_s + ((wv * 4 + k0) * 64 + lane) * 8) =
            *(const uint4*)(rowp + k0 * 32 + q * 8);
    __syncthreads();

    short8 bw[4];
    #pragma unroll
    for (int k0 = 0; k0 < 4; k0++)
        bw[k0] = *(const short8*)(Wfb + ((size_t)(wv * 4 + k0) * 64 + lane) * 8);

    float bv = bfv[wv * 16 + ln16];
    f32x4 acc[4];
    #pragma unroll
    for (int mt = 0; mt < 4; mt++) acc[mt] = (f32x4){bv, bv, bv, bv};

    #pragma unroll
    for (int k0 = 0; k0 < 4; k0++) {
        short8 af[4];
        #pragma unroll
        for (int mt = 0; mt < 4; mt++)
            af[mt] = *(const short8*)(A_s + ((mt * 4 + k0) * 64 + lane) * 8);
        #pragma unroll
        for (int mt = 0; mt < 4; mt++)
            acc[mt] = __builtin_amdgcn_mfma_f32_16x16x32_bf16(af[mt], bw[k0], acc[mt], 0, 0, 0);
    }

    const int col = (wv << 4) + ln16;
    #pragma unroll
    for (int mt = 0; mt < 4; mt++)
        #pragma unroll
        for (int r = 0; r < 4; r++) {
            int row = mt * 16 + q * 4 + r;
            float v = acc[mt][r];
            out[(size_t)(node0 + row) * FINAL + col] = v;
            XT[(size_t)(bloc * 64 + col) * 256 + (node0 & 255) + row] = to_bf16(v);
        }
}

// ---------- node1 (MFMA): out[:, :, 64:128] = DA @ nff per batch ----------
__global__ __launch_bounds__(256) void k_node1_mfma(
    const __hip_bfloat16* __restrict__ DAf,
    const __hip_bfloat16* __restrict__ XT,
    float* __restrict__ out)
{
    __shared__ __align__(16) __hip_bfloat16 B_s[32 * 512];
    const int blk = blockIdx.x;
    const int b = blk >> 2, i0 = (blk & 3) * 64;
    const int t = threadIdx.x;
    const int wv = t >> 6, lane = t & 63;
    const int q = lane >> 4, ln16 = lane & 15;

    const __hip_bfloat16* xrow = XT + (size_t)(b * 64 + (wv << 4) + ln16) * 256;
    #pragma unroll
    for (int k0 = 0; k0 < 8; k0++)
        *(uint4*)(B_s + ((wv * 8 + k0) * 64 + lane) * 8) =
            *(const uint4*)(xrow + k0 * 32 + q * 8);
    __syncthreads();

    f32x4 acc[4];
    #pragma unroll
    for (int mt = 0; mt < 4; mt++) acc[mt] = (f32x4){0.f, 0.f, 0.f, 0.f};

    #pragma unroll
    for (int k0 = 0; k0 < 8; k0++) {
        short8 bfr = *(const short8*)(B_s + ((wv * 8 + k0) * 64 + lane) * 8);
        short8 af[4];
        #pragma unroll
        for (int mt = 0; mt < 4; mt++)
            af[mt] = *(const short8*)(DAf + (size_t)(((i0 >> 4) + mt) * 8 + k0) * 512 + (lane << 3));
        #pragma unroll
        for (int mt = 0; mt < 4; mt++)
            acc[mt] = __builtin_amdgcn_mfma_f32_16x16x32_bf16(af[mt], bfr, acc[mt], 0, 0, 0);
    }

    #pragma unroll
    for (int mt = 0; mt < 4; mt++)
        #pragma unroll
        for (int r = 0; r < 4; r++) {
            int i = i0 + mt * 16 + q * 4 + r;
            out[(size_t)((b << 8) + i) * FINAL + 64 + (wv << 4) + ln16] = acc[mt][r];
        }
}

extern "C" void kernel_launch(void* const* d_in, const int* in_sizes, int n_in,
                              void* d_out, int out_size, void* d_ws, size_t ws_size,
                              hipStream_t stream)
{
    const float* node_fea = (const float*)d_in[0];
    const float* edge_fea = (const float*)d_in[1];
    const int*   eidx     = (const int*)  d_in[2];
    const float* dis      = (const float*)d_in[3];
    const float* Wn = (const float*)d_in[4];
    const float* bn = (const float*)d_in[5];
    const float* We = (const float*)d_in[6];
    const float* be = (const float*)d_in[7];
    const float* W1 = (const float*)d_in[8];
    const float* b1 = (const float*)d_in[9];
    const float* a1 = (const float*)d_in[10];
    const float* W2 = (const float*)d_in[11];
    const float* b2 = (const float*)d_in[12];
    const float* a2 = (const float*)d_in[13];
    const float* W3 = (const float*)d_in[14];
    const float* b3 = (const float*)d_in[15];
    const float* a3 = (const float*)d_in[16];
    const float* Wf = (const float*)d_in[17];
    const float* bf = (const float*)d_in[18];
    const float* DAw = (const float*)d_in[19];
    const float* DAb = (const float*)d_in[20];
    float* out = (float*)d_out;

    // workspace layout (bytes, 256-aligned blocks)
    char* base = (char*)d_ws;
    size_t off = 0;
    auto alloc = [&](size_t bytes) { char* p = base + off; off = (off + bytes + 255) & ~(size_t)255; return p; };
    __hip_bfloat16* nfA = (__hip_bfloat16*)alloc((size_t)Bb * Nn * NF * 2);
    __hip_bfloat16* nfB = (__hip_bfloat16*)alloc((size_t)Bb * Nn * NF * 2);
    __hip_bfloat16* W1b = (__hip_bfloat16*)alloc((size_t)SZ_WB * 2);
    __hip_bfloat16* W2b = (__hip_bfloat16*)alloc((size_t)SZ_WB * 2);
    __hip_bfloat16* W3b = (__hip_bfloat16*)alloc((size_t)SZ_WB * 2);
    __hip_bfloat16* W1s = (__hip_bfloat16*)alloc((size_t)SZ_WS * 2);
    __hip_bfloat16* W2s = (__hip_bfloat16*)alloc((size_t)SZ_WS * 2);
    __hip_bfloat16* W3s = (__hip_bfloat16*)alloc((size_t)SZ_WS * 2);
    float* WeT = (float*)alloc((size_t)OEF * EF * 4);
    __hip_bfloat16* DAf = (__hip_bfloat16*)alloc((size_t)Nn * Nn * 2);
    __hip_bfloat16* Wnb = (__hip_bfloat16*)alloc((size_t)SZ_WNB * 2);
    __hip_bfloat16* Web = (__hip_bfloat16*)alloc((size_t)SZ_WEB * 2);
    __hip_bfloat16* Wfb = (__hip_bfloat16*)alloc((size_t)SZ_WFB * 2);
    __hip_bfloat16* XT  = (__hip_bfloat16*)alloc((size_t)Bb * 64 * Nn * 2);
    __hip_bfloat16* efb = (__hip_bfloat16*)alloc((size_t)Bb * Nn * Mm * EF * 2);    // 33.5 MB
    const bool precomp = (ws_size >= off);

    hipLaunchKernelGGL(k_prep, dim3((PREP_TOTAL + 255) / 256), dim3(256), 0, stream,
                       We, W1, W2, W3, Wn, Wf, dis, DAw, DAb,
                       WeT, W1b, W2b, W3b, W1s, W2s, W3s, Wnb, Web, Wfb, DAf);

    hipLaunchKernelGGL(k_embed_all, dim3(precomp ? (256 + Bb * Nn * Mm / 64) : 256), dim3(256), 0, stream,
                       node_fea, Wnb, bn, nfA, edge_fea, Web, be, efb);

    if (precomp) {
        hipLaunchKernelGGL(k_conv_blk, dim3(Bb * Nn / NODESB), dim3(256), 0, stream,
                           nfA, efb, eidx, W1b, W1s, b1, a1, nfB);
        hipLaunchKernelGGL(k_conv_blk, dim3(Bb * Nn / NODESB), dim3(256), 0, stream,
                           nfB, efb, eidx, W2b, W2s, b2, a2, nfA);
        hipLaunchKernelGGL(k_conv_blk, dim3(Bb * Nn / NODESB), dim3(256), 0, stream,
                           nfA, efb, eidx, W3b, W3s, b3, a3, nfB);
    } else {
        hipLaunchKernelGGL((k_conv_mfma<false>), dim3(Bb * Nn / 4), dim3(256), 0, stream,
                           nfA, edge_fea, efb, eidx, WeT, be, W1b, W1s, b1, a1, nfB);
        hipLaunchKernelGGL((k_conv_mfma<false>), dim3(Bb * Nn / 4), dim3(256), 0, stream,
                           nfB, edge_fea, efb, eidx, WeT, be, W2b, W2s, b2, a2, nfA);
        hipLaunchKernelGGL((k_conv_mfma<false>), dim3(Bb * Nn / 4), dim3(256), 0, stream,
                           nfA, edge_fea, efb, eidx, WeT, be, W3b, W3s, b3, a3, nfB);
    }

    hipLaunchKernelGGL(k_final_mfma, dim3(Bb * Nn / 64), dim3(256), 0, stream, nfB, Wfb, bf, out, XT);
    hipLaunchKernelGGL(k_node1_mfma, dim3(Bb * 4), dim3(256), 0, stream, DAf, XT, out);
}

// Round 5
// 313.069 us; speedup vs baseline: 1.2390x; 1.0118x over previous
//
#include <hip/hip_runtime.h>
#include <hip/hip_bf16.h>
#include <math.h>

#define Bb   64
#define Nn   256
#define Mm   16
#define ONF  92
#define OEF  41
#define NF   128
#define EF   64
#define KDIM 320   // 2*NF + EF
#define ODIM 256   // 2*NF
#define FINAL 128
#define K0C  6     // conv K-chunks (K=192: gather 128 + edge 64)
#define NGRP  (Bb * Nn / 4)   // 4096 groups of 4 nodes
#define GRIDP 768             // persistent conv grid: exactly 3 blocks/CU

#define LOG2E_F 1.44269504088896f
#define LN2_F   0.6931471805599453f

typedef __attribute__((ext_vector_type(8))) short short8;
typedef __attribute__((ext_vector_type(4))) float f32x4;

#define AS1 __attribute__((address_space(1)))
#define AS3 __attribute__((address_space(3)))

// async global->LDS DMA, 16B per lane. LDS dest must be wave-uniform base + lane*16;
// global source is per-lane. Drained by the vmcnt(0) implicit in __syncthreads().
__device__ __forceinline__ void gl2lds16(const void* gp, void* lp) {
    __builtin_amdgcn_global_load_lds((AS1 void*)(void*)gp, (AS3 void*)lp, 16, 0, 0);
}
// pin a 128b value in VGPRs; placed INSIDE the loop it redefines the value each
// iteration so LLVM cannot rematerialize the original load (R2 lesson: VGPR=120
// proved the loads were being replayed per group).
#define KEEP8(x) asm volatile("" : "+v"(x))

__device__ __forceinline__ float sigmoidf_(float x) {
    float e = __expf(-x);
    return __builtin_amdgcn_rcpf(1.0f + e);
}
__device__ __forceinline__ float softplusf_(float x) {
    return fmaxf(x, 0.0f) + __logf(1.0f + __expf(-fabsf(x)));
}
__device__ __forceinline__ __hip_bfloat16 to_bf16(float x) { return __float2bfloat16(x); }

// ---------- mega-prep: all weight swizzles + WeT + DA in ONE launch ----------
__device__ __forceinline__ void swz(const float* __restrict__ in, __hip_bfloat16* __restrict__ out,
                                    int t, int Itot, int koff, int Kuse, int K0, float scale)
{
    int j = t & 7;
    int u = t >> 3;
    int lane = u & 63;
    int ln16 = lane & 15, q = lane >> 4;
    int v = u >> 6;
    int k0 = v % K0, tile = v / K0;
    int n = tile * 16 + ln16, k = k0 * 32 + q * 8 + j;
    out[t] = (k < Kuse) ? to_bf16(scale * in[(size_t)n * Itot + koff + k]) : to_bf16(0.0f);
}

#define SZ_WET (OEF * EF)          // 2624
#define SZ_WB  (16 * K0C * 512)    // 49152
#define SZ_WS  (16 * 4 * 512)      // 32768
#define SZ_WNB ((NF / 16) * 3 * 512)
#define SZ_WEB ((EF / 16) * 2 * 512)
#define SZ_WFB ((64 / 16) * 4 * 512)
#define SZ_DA  (Nn * Nn)
#define PREP_TOTAL (SZ_WET + 3 * SZ_WB + 3 * SZ_WS + SZ_WNB + SZ_WEB + SZ_WFB + SZ_DA)

__global__ __launch_bounds__(256) void k_prep(
    const float* __restrict__ We, const float* __restrict__ W1,
    const float* __restrict__ W2, const float* __restrict__ W3,
    const float* __restrict__ Wn, const float* __restrict__ Wf,
    const float* __restrict__ dis, const float* __restrict__ pw, const float* __restrict__ pb,
    float* __restrict__ WeT,
    __hip_bfloat16* __restrict__ W1b, __hip_bfloat16* __restrict__ W2b, __hip_bfloat16* __restrict__ W3b,
    __hip_bfloat16* __restrict__ W1s, __hip_bfloat16* __restrict__ W2s, __hip_bfloat16* __restrict__ W3s,
    __hip_bfloat16* __restrict__ Wnb, __hip_bfloat16* __restrict__ Web, __hip_bfloat16* __restrict__ Wfb,
    __hip_bfloat16* __restrict__ DAf)
{
    int t = blockIdx.x * 256 + threadIdx.x;
    if (t < SZ_WET) {
        int o = t / OEF, i = t - o * OEF;
        WeT[i * EF + o] = We[t];
        return;
    }
    t -= SZ_WET;
    if (t < SZ_WB) { swz(W1, W1b, t, KDIM, NF, 192, K0C, LOG2E_F); return; }
    t -= SZ_WB;
    if (t < SZ_WB) { swz(W2, W2b, t, KDIM, NF, 192, K0C, LOG2E_F); return; }
    t -= SZ_WB;
    if (t < SZ_WB) { swz(W3, W3b, t, KDIM, NF, 192, K0C, LOG2E_F); return; }
    t -= SZ_WB;
    if (t < SZ_WS) { swz(W1, W1s, t, KDIM, 0, NF, 4, LOG2E_F); return; }
    t -= SZ_WS;
    if (t < SZ_WS) { swz(W2, W2s, t, KDIM, 0, NF, 4, LOG2E_F); return; }
    t -= SZ_WS;
    if (t < SZ_WS) { swz(W3, W3s, t, KDIM, 0, NF, 4, LOG2E_F); return; }
    t -= SZ_WS;
    if (t < SZ_WNB) { swz(Wn, Wnb, t, ONF, 0, ONF, 3, 1.0f); return; }
    t -= SZ_WNB;
    if (t < SZ_WEB) { swz(We, Web, t, OEF, 0, OEF, 2, 1.0f); return; }
    t -= SZ_WEB;
    if (t < SZ_WFB) { swz(Wf, Wfb, t, NF, 0, NF, 4, 1.0f); return; }
    t -= SZ_WFB;
    if (t < SZ_DA) {
        int i = t >> 8, jx = t & 255;
        float v = sigmoidf_(fmaf(*pw, dis[t], *pb));
        int itile = i >> 4, ln16 = i & 15;
        int k0 = jx >> 5, q = (jx >> 3) & 3, jj = jx & 7;
        DAf[(size_t)((((itile * 8 + k0) << 6) + (q << 4) + ln16)) * 8 + jj] = to_bf16(v);
    }
}

// ---------- generic MFMA embed body ----------
template<int KIN, int K0, int NCOLS>
__device__ __forceinline__ void emb_body(
    int bid, const float* __restrict__ X, const __hip_bfloat16* __restrict__ Bswz,
    const float* __restrict__ bias, __hip_bfloat16* __restrict__ Y,
    __hip_bfloat16* A_s, __hip_bfloat16* O_s)
{
    constexpr int KP = K0 * 32;
    constexpr int TPW = NCOLS / 64;
    constexpr int OLD = NCOLS + 24;

    const int row0 = bid * 64;
    const int t = threadIdx.x;

    {
        const float4* Xb = (const float4*)(X + (size_t)row0 * KIN);
        constexpr int NV = (64 * KIN) / 4;
        for (int c = t; c < NV; c += 256) {
            float4 v = Xb[c];
            int flat = c * 4;
            #pragma unroll
            for (int e = 0; e < 4; e++) {
                int f = flat + e;
                int row = f / KIN, k = f - row * KIN;
                int mt = row >> 4, ln16 = row & 15;
                int k0 = k >> 5, q = (k >> 3) & 3, j = k & 7;
                float vv = (e == 0) ? v.x : (e == 1) ? v.y : (e == 2) ? v.z : v.w;
                A_s[(((mt * K0 + k0) << 6) + (q << 4) + ln16) * 8 + j] = to_bf16(vv);
            }
        }
        constexpr int PAD = KP - KIN;
        for (int c = t; c < 64 * PAD; c += 256) {
            int row = c / PAD, k = KIN + (c - row * PAD);
            int mt = row >> 4, ln16 = row & 15;
            int k0 = k >> 5, q = (k >> 3) & 3, j = k & 7;
            A_s[(((mt * K0 + k0) << 6) + (q << 4) + ln16) * 8 + j] = to_bf16(0.0f);
        }
    }
    __syncthreads();

    const int wv = t >> 6, lane = t & 63;
    const int q = lane >> 4, ln16 = lane & 15;

    f32x4 acc[4][TPW];
    #pragma unroll
    for (int p = 0; p < TPW; p++) {
        float bv = bias[(wv * TPW + p) * 16 + ln16];
        #pragma unroll
        for (int mt = 0; mt < 4; mt++) acc[mt][p] = (f32x4){bv, bv, bv, bv};
    }

    short8 bw[TPW][K0];
    #pragma unroll
    for (int p = 0; p < TPW; p++)
        #pragma unroll
        for (int k0 = 0; k0 < K0; k0++)
            bw[p][k0] = *(const short8*)(Bswz + ((size_t)((wv * TPW + p) * K0 + k0) << 9) + (lane << 3));

    #pragma unroll
    for (int k0 = 0; k0 < K0; k0++) {
        short8 af[4];
        #pragma unroll
        for (int mt = 0; mt < 4; mt++)
            af[mt] = *(const short8*)(A_s + (((mt * K0 + k0) << 6) + lane) * 8);
        #pragma unroll
        for (int mt = 0; mt < 4; mt++)
            #pragma unroll
            for (int p = 0; p < TPW; p++)
                acc[mt][p] = __builtin_amdgcn_mfma_f32_16x16x32_bf16(af[mt], bw[p][k0], acc[mt][p], 0, 0, 0);
    }

    #pragma unroll
    for (int mt = 0; mt < 4; mt++)
        #pragma unroll
        for (int p = 0; p < TPW; p++) {
            int col = (wv * TPW + p) * 16 + ln16;
            #pragma unroll
            for (int r = 0; r < 4; r++)
                O_s[(mt * 16 + q * 4 + r) * OLD + col] = to_bf16(acc[mt][p][r]);
        }
    __syncthreads();
    constexpr int CH = NCOLS / 8;
    for (int c = t; c < 64 * CH; c += 256) {
        int row = c / CH, ch = c - row * CH;
        *(uint4*)(Y + (size_t)(row0 + row) * NCOLS + ch * 8) =
            *(const uint4*)(O_s + row * OLD + ch * 8);
    }
}

// blocks [0,256): node embed; [256, 256+4096): edge embed
__global__ __launch_bounds__(256) void k_embed_all(
    const float* __restrict__ node_fea, const __hip_bfloat16* __restrict__ Wnb,
    const float* __restrict__ bn, __hip_bfloat16* __restrict__ nf0,
    const float* __restrict__ edge_fea, const __hip_bfloat16* __restrict__ Web,
    const float* __restrict__ be, __hip_bfloat16* __restrict__ efb)
{
    __shared__ __align__(16) __hip_bfloat16 A_s[4 * 3 * 512];
    __shared__ __align__(16) __hip_bfloat16 O_s[64 * (NF + 24)];
    if (blockIdx.x < 256)
        emb_body<ONF, 3, NF>(blockIdx.x, node_fea, Wnb, bn, nf0, A_s, O_s);
    else
        emb_body<OEF, 2, EF>(blockIdx.x - 256, edge_fea, Web, be, efb, A_s, O_s);
}

// ---------- S GEMM: S[n][o] = log2e*(nf[n] @ Wself[o] + bias[o]), f32 out ----------
// [16384 x 128] @ [128 x 256]. 64 rows/block, grid 256. Ws = [16][4][512] log2e-scaled.
__global__ __launch_bounds__(256) void k_gemm_s(
    const __hip_bfloat16* __restrict__ nf,
    const __hip_bfloat16* __restrict__ Ws,
    const float* __restrict__ bias,
    float* __restrict__ S)
{
    __shared__ __align__(16) __hip_bfloat16 A_s[16 * 512];
    const int row0 = blockIdx.x * 64;
    const int t = threadIdx.x;
    const int wv = t >> 6, lane = t & 63;
    const int q = lane >> 4, ln16 = lane & 15;

    #pragma unroll
    for (int k0 = 0; k0 < 4; k0++)
        gl2lds16(nf + (size_t)(row0 + (wv << 4) + ln16) * NF + k0 * 32 + q * 8,
                 A_s + ((wv * 4 + k0) * 64 + lane) * 8);
    __syncthreads();

    short8 bw[4][4];
    #pragma unroll
    for (int p = 0; p < 4; p++)
        #pragma unroll
        for (int k0 = 0; k0 < 4; k0++)
            bw[p][k0] = *(const short8*)(Ws + ((size_t)((wv * 4 + p) * 4 + k0) << 9) + (lane << 3));

    f32x4 acc[4][4];
    #pragma unroll
    for (int p = 0; p < 4; p++) {
        float bv = bias[(wv * 4 + p) * 16 + ln16] * LOG2E_F;
        #pragma unroll
        for (int mt = 0; mt < 4; mt++) acc[mt][p] = (f32x4){bv, bv, bv, bv};
    }

    #pragma unroll
    for (int k0 = 0; k0 < 4; k0++) {
        short8 af[4];
        #pragma unroll
        for (int mt = 0; mt < 4; mt++)
            af[mt] = *(const short8*)(A_s + ((mt * 4 + k0) * 64 + lane) * 8);
        #pragma unroll
        for (int mt = 0; mt < 4; mt++)
            #pragma unroll
            for (int p = 0; p < 4; p++)
                acc[mt][p] = __builtin_amdgcn_mfma_f32_16x16x32_bf16(af[mt], bw[p][k0], acc[mt][p], 0, 0, 0);
    }

    #pragma unroll
    for (int mt = 0; mt < 4; mt++)
        #pragma unroll
        for (int p = 0; p < 4; p++) {
            int col = (wv * 4 + p) * 16 + ln16;
            #pragma unroll
            for (int r = 0; r < 4; r++)
                S[(size_t)(row0 + mt * 16 + q * 4 + r) * ODIM + col] = acc[mt][p][r];
        }
}

// ---------- persistent conv layer (PRECOMP path) ----------
// Grid 768 = exactly 3 blocks/CU (LDS 48KB, VGPR<=170 via launch_bounds(256,3)).
// Each block loops groups g += 768: weights loaded ONCE per block and re-pinned
// per iteration (KEEP8 in-loop blocks rematerialization). Self-term comes from
// the precomputed S buffer (per-node, f32) -> no self phase, no Wsb traffic,
// no sv shuffles. A-tile double-buffered via global_load_lds; one barrier/group.
__global__ __launch_bounds__(256, 3) void k_conv_ps(
    const __hip_bfloat16* __restrict__ nf_in,   // [B*N][NF] bf16
    const __hip_bfloat16* __restrict__ ef_bf,   // [B*N*M][EF] bf16
    const int*   __restrict__ eidx,             // [B*N][M]
    const __hip_bfloat16* __restrict__ Wb,      // [16][K0C][64][8] (log2e*W[:,128:320])
    const float* __restrict__ Sbuf,             // [B*N][ODIM] f32 = log2e*(self+bias)
    const float* __restrict__ palpha,
    __hip_bfloat16* __restrict__ nf_out)        // [B*N][NF] bf16
{
    __shared__ __align__(16) __hip_bfloat16 A_s[2][4 * K0C * 512];  // 2 x 24576 B

    const int t = threadIdx.x;
    const int wv = t >> 6, lane = t & 63;
    const int q = lane >> 4, ln16 = lane & 15;
    const int row = (wv << 4) + ln16;                // lane's edge-row within a group
    const float alpha = *palpha;

    // ---- stage helper: gather + edge fragments of group gi into buf
    auto stage_group = [&](int gi, __hip_bfloat16* buf) -> unsigned long long {
        const int node0g = gi * 4;
        const int bbase = node0g & ~255;
        int mi = eidx[node0g * Mm + row];
        unsigned long long mb = __ballot(eidx[node0g * Mm + lane] >= 0);
        int j = mi < 0 ? 0 : mi;
        const __hip_bfloat16* gathp = nf_in + (size_t)(bbase + j) * NF + q * 8;
        #pragma unroll
        for (int k0 = 0; k0 < 4; k0++)
            gl2lds16(gathp + k0 * 32, buf + (wv * K0C + k0) * 512 + lane * 8);
        const __hip_bfloat16* efp = ef_bf + (size_t)((node0g << 4) + row) * EF + q * 8;
        #pragma unroll
        for (int k0 = 0; k0 < 2; k0++)
            gl2lds16(efp + k0 * 32, buf + (wv * K0C + 4 + k0) * 512 + lane * 8);
        return mb;
    };

    // ---- weight preload: ONCE per persistent block (96 VGPR)
    const __hip_bfloat16* WF0 = Wb + ((size_t)(2 * wv) * (K0C * 512)) + (lane << 3);
    const __hip_bfloat16* WF1 = WF0 + K0C * 512;
    const __hip_bfloat16* WC0 = WF0 + 8 * (K0C * 512);
    const __hip_bfloat16* WC1 = WC0 + K0C * 512;
    short8 mF0[K0C], mF1[K0C], mC0[K0C], mC1[K0C];
    #pragma unroll
    for (int k0 = 0; k0 < K0C; k0++) {
        mF0[k0] = *(const short8*)(WF0 + k0 * 512);
        mF1[k0] = *(const short8*)(WF1 + k0 * 512);
        mC0[k0] = *(const short8*)(WC0 + k0 * 512);
        mC1[k0] = *(const short8*)(WC1 + k0 * 512);
    }

    int g = blockIdx.x;
    unsigned long long mb_pending = stage_group(g, A_s[0]);
    int cur = 0;

    for (; g < NGRP; g += GRIDP) {
        __syncthreads();   // drains this wave's DMAs for A_s[cur]; all waves past prev compute

        const unsigned long long mb_now = mb_pending;
        if (g + GRIDP < NGRP) mb_pending = stage_group(g + GRIDP, A_s[cur ^ 1]);

        // re-pin weights each iteration: asm redefinition kills rematerialization
        #pragma unroll
        for (int k0 = 0; k0 < K0C; k0++) {
            KEEP8(mF0[k0]); KEEP8(mF1[k0]); KEEP8(mC0[k0]); KEEP8(mC1[k0]);
        }

        const int node0g = g * 4;
        const __hip_bfloat16* Acur = A_s[cur];

        // per-mt processing keeps live acc at 16 regs (VGPR budget: 96 W + ~50 rest)
        #pragma unroll
        for (int mt = 0; mt < 4; mt++) {
            const int gnode = node0g + mt;
            // acc init from precomputed S (uniform across q -> L1 broadcast)
            const float* Srow = Sbuf + (size_t)gnode * ODIM;
            f32x4 accF[2], accC[2];
            float selfv[2];
            #pragma unroll
            for (int p = 0; p < 2; p++) {
                int col = (2 * wv + p) * 16 + ln16;
                float vF = Srow[col];
                float vC = Srow[128 + col];
                accF[p] = (f32x4){vF, vF, vF, vF};
                accC[p] = (f32x4){vC, vC, vC, vC};
                selfv[p] = __bfloat162float(nf_in[(size_t)gnode * NF + col]);
            }
            // K-loop: pure LDS + MFMA, weights in pinned regs
            #pragma unroll
            for (int k0 = 0; k0 < K0C; k0++) {
                short8 af = *(const short8*)(Acur + ((mt * K0C + k0) * 64 + lane) * 8);
                accF[0] = __builtin_amdgcn_mfma_f32_16x16x32_bf16(af, mF0[k0], accF[0], 0, 0, 0);
                accF[1] = __builtin_amdgcn_mfma_f32_16x16x32_bf16(af, mF1[k0], accF[1], 0, 0, 0);
                accC[0] = __builtin_amdgcn_mfma_f32_16x16x32_bf16(af, mC0[k0], accC[0], 0, 0, 0);
                accC[1] = __builtin_amdgcn_mfma_f32_16x16x32_bf16(af, mC1[k0], accC[1], 0, 0, 0);
            }
            // epilogue (log2-domain)
            unsigned mbits = (unsigned)(mb_now >> (mt * 16 + q * 4)) & 0xFu;
            #pragma unroll
            for (int p = 0; p < 2; p++) {
                float partial = 0.0f;
                #pragma unroll
                for (int r = 0; r < 4; r++) {
                    bool msk = (mbits >> r) & 1u;
                    float f2 = accF[p][r];
                    float c2 = accC[p][r];
                    float sig = __builtin_amdgcn_rcpf(1.0f + __builtin_amdgcn_exp2f(-f2));
                    float sp2 = fmaxf(c2, 0.0f) +
                                __builtin_amdgcn_logf(1.0f + __builtin_amdgcn_exp2f(-fabsf(c2)));
                    partial += msk ? sig * sp2 : 0.0f;
                }
                partial += __shfl_xor(partial, 16);
                partial += __shfl_xor(partial, 32);
                if (q == 0) {
                    int col = (2 * wv + p) * 16 + ln16;
                    nf_out[(size_t)gnode * NF + col] =
                        to_bf16(softplusf_(fmaf(alpha, selfv[p], LN2_F * partial)));
                }
            }
        }
        cur ^= 1;
    }
}

// ---------- fallback conv layer (non-precomp path; unchanged) ----------
template<bool PRECOMP>
__global__ __launch_bounds__(256, 3) void k_conv_mfma(
    const __hip_bfloat16* __restrict__ nf_in,
    const float* __restrict__ edge_fea,
    const __hip_bfloat16* __restrict__ ef_bf,
    const int*   __restrict__ eidx,
    const float* __restrict__ WeT,
    const float* __restrict__ be,
    const __hip_bfloat16* __restrict__ Wb,
    const __hip_bfloat16* __restrict__ Wsb,
    const float* __restrict__ bias,
    const float* __restrict__ palpha,
    __hip_bfloat16* __restrict__ nf_out)
{
    __shared__ __align__(16) __hip_bfloat16 A_s[4 * K0C * 512];
    __shared__ __align__(16) __hip_bfloat16 A_sf[4 * 512];

    const int node0 = blockIdx.x * 4;
    const int b = node0 >> 8;
    const int t = threadIdx.x;
    const int wv = t >> 6, lane = t & 63;
    const int q = lane >> 4, ln16 = lane & 15;
    const int row = (wv << 4) + ln16;

    const int myidx = eidx[node0 * Mm + row];
    const unsigned long long mball = __ballot(eidx[node0 * Mm + lane] >= 0);

    float selfv[8];
    #pragma unroll
    for (int mt = 0; mt < 4; mt++)
        #pragma unroll
        for (int p = 0; p < 2; p++)
            selfv[mt * 2 + p] =
                __bfloat162float(nf_in[(size_t)(node0 + mt) * NF + (2 * wv + p) * 16 + ln16]);

    {
        int j = myidx < 0 ? 0 : myidx;
        const __hip_bfloat16* gathp = nf_in + (size_t)((b << 8) + j) * NF;
        #pragma unroll
        for (int k0 = 0; k0 < 4; k0++)
            *(uint4*)(A_s + ((wv * K0C + k0) * 64 + lane) * 8) =
                *(const uint4*)(gathp + k0 * 32 + q * 8);
        *(uint4*)(A_sf + (wv * 64 + lane) * 8) =
            *(const uint4*)(nf_in + (size_t)(node0 + (ln16 & 3)) * NF + wv * 32 + q * 8);
        if (PRECOMP) {
            const __hip_bfloat16* efp = ef_bf + (size_t)((node0 << 4) + row) * EF;
            #pragma unroll
            for (int k0 = 0; k0 < 2; k0++)
                *(uint4*)(A_s + ((wv * K0C + 4 + k0) * 64 + lane) * 8) =
                    *(const uint4*)(efp + k0 * 32 + q * 8);
        } else {
            for (int c = t; c < 64 * EF; c += 256) {
                int rr = c >> 6, col = c & 63;
                float a = be[col];
                const float* er = edge_fea + (size_t)(node0 * Mm + rr) * OEF;
                #pragma unroll
                for (int i = 0; i < OEF; i++) a = fmaf(er[i], WeT[i * EF + col], a);
                int mt = rr >> 4, l16 = rr & 15;
                int k0 = 4 + (col >> 5), qq = (col >> 3) & 3, jj = col & 7;
                A_s[((mt * K0C + k0) * 64 + qq * 16 + l16) * 8 + jj] = to_bf16(a);
            }
        }
    }
    __syncthreads();

    f32x4 sv[4];
    #pragma unroll
    for (int c = 0; c < 4; c++) {
        int tile = 2 * wv + (c & 1) + ((c >> 1) << 3);
        float bv = bias[tile * 16 + ln16] * LOG2E_F;
        sv[c] = (f32x4){bv, bv, bv, bv};
    }
    #pragma unroll
    for (int k0 = 0; k0 < 4; k0++) {
        short8 afs = *(const short8*)(A_sf + (k0 * 64 + lane) * 8);
        #pragma unroll
        for (int c = 0; c < 4; c++) {
            int tile = 2 * wv + (c & 1) + ((c >> 1) << 3);
            short8 bws = *(const short8*)(Wsb + ((size_t)(tile * 4 + k0) << 9) + (lane << 3));
            sv[c] = __builtin_amdgcn_mfma_f32_16x16x32_bf16(afs, bws, sv[c], 0, 0, 0);
        }
    }

    f32x4 accF[4][2], accC[4][2];
    #pragma unroll
    for (int mt = 0; mt < 4; mt++) {
        #pragma unroll
        for (int p = 0; p < 2; p++) {
            float vF = __shfl(sv[p][mt], ln16);
            float vC = __shfl(sv[2 + p][mt], ln16);
            accF[mt][p] = (f32x4){vF, vF, vF, vF};
            accC[mt][p] = (f32x4){vC, vC, vC, vC};
        }
    }

    const __hip_bfloat16* WF0 = Wb + ((size_t)(2 * wv) * (K0C * 512)) + (lane << 3);
    const __hip_bfloat16* WF1 = WF0 + K0C * 512;
    const __hip_bfloat16* WC0 = WF0 + 8 * (K0C * 512);
    const __hip_bfloat16* WC1 = WC0 + K0C * 512;

    #pragma unroll
    for (int k0 = 0; k0 < K0C; k0++) {
        short8 cF0 = *(const short8*)(WF0 + k0 * 512);
        short8 cF1 = *(const short8*)(WF1 + k0 * 512);
        short8 cC0 = *(const short8*)(WC0 + k0 * 512);
        short8 cC1 = *(const short8*)(WC1 + k0 * 512);
        short8 af[4];
        #pragma unroll
        for (int mt = 0; mt < 4; mt++)
            af[mt] = *(const short8*)(A_s + ((mt * K0C + k0) * 64 + lane) * 8);
        #pragma unroll
        for (int mt = 0; mt < 4; mt++) {
            accF[mt][0] = __builtin_amdgcn_mfma_f32_16x16x32_bf16(af[mt], cF0, accF[mt][0], 0, 0, 0);
            accF[mt][1] = __builtin_amdgcn_mfma_f32_16x16x32_bf16(af[mt], cF1, accF[mt][1], 0, 0, 0);
            accC[mt][0] = __builtin_amdgcn_mfma_f32_16x16x32_bf16(af[mt], cC0, accC[mt][0], 0, 0, 0);
            accC[mt][1] = __builtin_amdgcn_mfma_f32_16x16x32_bf16(af[mt], cC1, accC[mt][1], 0, 0, 0);
        }
    }

    const float alpha = *palpha;
    #pragma unroll
    for (int mt = 0; mt < 4; mt++) {
        const int gnode = node0 + mt;
        unsigned mbits = (unsigned)(mball >> (mt * 16 + q * 4)) & 0xFu;
        #pragma unroll
        for (int p = 0; p < 2; p++) {
            float partial = 0.0f;
            #pragma unroll
            for (int r = 0; r < 4; r++) {
                bool msk = (mbits >> r) & 1u;
                float f2 = accF[mt][p][r];
                float c2 = accC[mt][p][r];
                float sig = __builtin_amdgcn_rcpf(1.0f + __builtin_amdgcn_exp2f(-f2));
                float sp2 = fmaxf(c2, 0.0f) +
                            __builtin_amdgcn_logf(1.0f + __builtin_amdgcn_exp2f(-fabsf(c2)));
                partial += msk ? sig * sp2 : 0.0f;
            }
            partial += __shfl_xor(partial, 16);
            partial += __shfl_xor(partial, 32);
            if (q == 0) {
                int col = (2 * wv + p) * 16 + ln16;
                nf_out[(size_t)gnode * NF + col] =
                    to_bf16(softplusf_(fmaf(alpha, selfv[mt * 2 + p], LN2_F * partial)));
            }
        }
    }
}

// ---------- final linear (MFMA): out[:, :, 0:64] = nf3 @ Wf^T + bf ----------
__global__ __launch_bounds__(256) void k_final_mfma(
    const __hip_bfloat16* __restrict__ nf, const __hip_bfloat16* __restrict__ Wfb,
    const float* __restrict__ bfv, float* __restrict__ out,
    __hip_bfloat16* __restrict__ XT)
{
    __shared__ __align__(16) __hip_bfloat16 A_s[16 * 512];
    const int node0 = blockIdx.x * 64;
    const int bloc = node0 >> 8;
    const int t = threadIdx.x;
    const int wv = t >> 6, lane = t & 63;
    const int q = lane >> 4, ln16 = lane & 15;

    const __hip_bfloat16* rowp = nf + (size_t)(node0 + (wv << 4) + ln16) * NF;
    #pragma unroll
    for (int k0 = 0; k0 < 4; k0++)
        *(uint4*)(A_s + ((wv * 4 + k0) * 64 + lane) * 8) =
            *(const uint4*)(rowp + k0 * 32 + q * 8);
    __syncthreads();

    short8 bw[4];
    #pragma unroll
    for (int k0 = 0; k0 < 4; k0++)
        bw[k0] = *(const short8*)(Wfb + ((size_t)(wv * 4 + k0) * 64 + lane) * 8);

    float bv = bfv[wv * 16 + ln16];
    f32x4 acc[4];
    #pragma unroll
    for (int mt = 0; mt < 4; mt++) acc[mt] = (f32x4){bv, bv, bv, bv};

    #pragma unroll
    for (int k0 = 0; k0 < 4; k0++) {
        short8 af[4];
        #pragma unroll
        for (int mt = 0; mt < 4; mt++)
            af[mt] = *(const short8*)(A_s + ((mt * 4 + k0) * 64 + lane) * 8);
        #pragma unroll
        for (int mt = 0; mt < 4; mt++)
            acc[mt] = __builtin_amdgcn_mfma_f32_16x16x32_bf16(af[mt], bw[k0], acc[mt], 0, 0, 0);
    }

    const int col = (wv << 4) + ln16;
    #pragma unroll
    for (int mt = 0; mt < 4; mt++)
        #pragma unroll
        for (int r = 0; r < 4; r++) {
            int row = mt * 16 + q * 4 + r;
            float v = acc[mt][r];
            out[(size_t)(node0 + row) * FINAL + col] = v;
            XT[(size_t)(bloc * 64 + col) * 256 + (node0 & 255) + row] = to_bf16(v);
        }
}

// ---------- node1 (MFMA): out[:, :, 64:128] = DA @ nff per batch ----------
__global__ __launch_bounds__(256) void k_node1_mfma(
    const __hip_bfloat16* __restrict__ DAf,
    const __hip_bfloat16* __restrict__ XT,
    float* __restrict__ out)
{
    __shared__ __align__(16) __hip_bfloat16 B_s[32 * 512];
    const int blk = blockIdx.x;
    const int b = blk >> 2, i0 = (blk & 3) * 64;
    const int t = threadIdx.x;
    const int wv = t >> 6, lane = t & 63;
    const int q = lane >> 4, ln16 = lane & 15;

    const __hip_bfloat16* xrow = XT + (size_t)(b * 64 + (wv << 4) + ln16) * 256;
    #pragma unroll
    for (int k0 = 0; k0 < 8; k0++)
        *(uint4*)(B_s + ((wv * 8 + k0) * 64 + lane) * 8) =
            *(const uint4*)(xrow + k0 * 32 + q * 8);
    __syncthreads();

    f32x4 acc[4];
    #pragma unroll
    for (int mt = 0; mt < 4; mt++) acc[mt] = (f32x4){0.f, 0.f, 0.f, 0.f};

    #pragma unroll
    for (int k0 = 0; k0 < 8; k0++) {
        short8 bfr = *(const short8*)(B_s + ((wv * 8 + k0) * 64 + lane) * 8);
        short8 af[4];
        #pragma unroll
        for (int mt = 0; mt < 4; mt++)
            af[mt] = *(const short8*)(DAf + (size_t)(((i0 >> 4) + mt) * 8 + k0) * 512 + (lane << 3));
        #pragma unroll
        for (int mt = 0; mt < 4; mt++)
            acc[mt] = __builtin_amdgcn_mfma_f32_16x16x32_bf16(af[mt], bfr, acc[mt], 0, 0, 0);
    }

    #pragma unroll
    for (int mt = 0; mt < 4; mt++)
        #pragma unroll
        for (int r = 0; r < 4; r++) {
            int i = i0 + mt * 16 + q * 4 + r;
            out[(size_t)((b << 8) + i) * FINAL + 64 + (wv << 4) + ln16] = acc[mt][r];
        }
}

extern "C" void kernel_launch(void* const* d_in, const int* in_sizes, int n_in,
                              void* d_out, int out_size, void* d_ws, size_t ws_size,
                              hipStream_t stream)
{
    const float* node_fea = (const float*)d_in[0];
    const float* edge_fea = (const float*)d_in[1];
    const int*   eidx     = (const int*)  d_in[2];
    const float* dis      = (const float*)d_in[3];
    const float* Wn = (const float*)d_in[4];
    const float* bn = (const float*)d_in[5];
    const float* We = (const float*)d_in[6];
    const float* be = (const float*)d_in[7];
    const float* W1 = (const float*)d_in[8];
    const float* b1 = (const float*)d_in[9];
    const float* a1 = (const float*)d_in[10];
    const float* W2 = (const float*)d_in[11];
    const float* b2 = (const float*)d_in[12];
    const float* a2 = (const float*)d_in[13];
    const float* W3 = (const float*)d_in[14];
    const float* b3 = (const float*)d_in[15];
    const float* a3 = (const float*)d_in[16];
    const float* Wf = (const float*)d_in[17];
    const float* bf = (const float*)d_in[18];
    const float* DAw = (const float*)d_in[19];
    const float* DAb = (const float*)d_in[20];
    float* out = (float*)d_out;

    // workspace layout (bytes, 256-aligned blocks)
    char* base = (char*)d_ws;
    size_t off = 0;
    auto alloc = [&](size_t bytes) { char* p = base + off; off = (off + bytes + 255) & ~(size_t)255; return p; };
    __hip_bfloat16* nfA = (__hip_bfloat16*)alloc((size_t)Bb * Nn * NF * 2);
    __hip_bfloat16* nfB = (__hip_bfloat16*)alloc((size_t)Bb * Nn * NF * 2);
    __hip_bfloat16* W1b = (__hip_bfloat16*)alloc((size_t)SZ_WB * 2);
    __hip_bfloat16* W2b = (__hip_bfloat16*)alloc((size_t)SZ_WB * 2);
    __hip_bfloat16* W3b = (__hip_bfloat16*)alloc((size_t)SZ_WB * 2);
    __hip_bfloat16* W1s = (__hip_bfloat16*)alloc((size_t)SZ_WS * 2);
    __hip_bfloat16* W2s = (__hip_bfloat16*)alloc((size_t)SZ_WS * 2);
    __hip_bfloat16* W3s = (__hip_bfloat16*)alloc((size_t)SZ_WS * 2);
    float* WeT = (float*)alloc((size_t)OEF * EF * 4);
    __hip_bfloat16* DAf = (__hip_bfloat16*)alloc((size_t)Nn * Nn * 2);
    __hip_bfloat16* Wnb = (__hip_bfloat16*)alloc((size_t)SZ_WNB * 2);
    __hip_bfloat16* Web = (__hip_bfloat16*)alloc((size_t)SZ_WEB * 2);
    __hip_bfloat16* Wfb = (__hip_bfloat16*)alloc((size_t)SZ_WFB * 2);
    __hip_bfloat16* XT  = (__hip_bfloat16*)alloc((size_t)Bb * 64 * Nn * 2);
    __hip_bfloat16* efb = (__hip_bfloat16*)alloc((size_t)Bb * Nn * Mm * EF * 2);    // 33.5 MB
    float* Sbuf = (float*)alloc((size_t)Bb * Nn * ODIM * 4);                        // 16.8 MB
    const bool precomp = (ws_size >= off);

    hipLaunchKernelGGL(k_prep, dim3((PREP_TOTAL + 255) / 256), dim3(256), 0, stream,
                       We, W1, W2, W3, Wn, Wf, dis, DAw, DAb,
                       WeT, W1b, W2b, W3b, W1s, W2s, W3s, Wnb, Web, Wfb, DAf);

    hipLaunchKernelGGL(k_embed_all, dim3(precomp ? (256 + Bb * Nn * Mm / 64) : 256), dim3(256), 0, stream,
                       node_fea, Wnb, bn, nfA, edge_fea, Web, be, efb);

    if (precomp) {
        hipLaunchKernelGGL(k_gemm_s, dim3(Bb * Nn / 64), dim3(256), 0, stream,
                           nfA, W1s, b1, Sbuf);
        hipLaunchKernelGGL(k_conv_ps, dim3(GRIDP), dim3(256), 0, stream,
                           nfA, efb, eidx, W1b, Sbuf, a1, nfB);
        hipLaunchKernelGGL(k_gemm_s, dim3(Bb * Nn / 64), dim3(256), 0, stream,
                           nfB, W2s, b2, Sbuf);
        hipLaunchKernelGGL(k_conv_ps, dim3(GRIDP), dim3(256), 0, stream,
                           nfB, efb, eidx, W2b, Sbuf, a2, nfA);
        hipLaunchKernelGGL(k_gemm_s, dim3(Bb * Nn / 64), dim3(256), 0, stream,
                           nfA, W3s, b3, Sbuf);
        hipLaunchKernelGGL(k_conv_ps, dim3(GRIDP), dim3(256), 0, stream,
                           nfA, efb, eidx, W3b, Sbuf, a3, nfB);
    } else {
        hipLaunchKernelGGL((k_conv_mfma<false>), dim3(Bb * Nn / 4), dim3(256), 0, stream,
                           nfA, edge_fea, efb, eidx, WeT, be, W1b, W1s, b1, a1, nfB);
        hipLaunchKernelGGL((k_conv_mfma<false>), dim3(Bb * Nn / 4), dim3(256), 0, stream,
                           nfB, edge_fea, efb, eidx, WeT, be, W2b, W2s, b2, a2, nfA);
        hipLaunchKernelGGL((k_conv_mfma<false>), dim3(Bb * Nn / 4), dim3(256), 0, stream,
                           nfA, edge_fea, efb, eidx, WeT, be, W3b, W3s, b3, a3, nfB);
    }

    hipLaunchKernelGGL(k_final_mfma, dim3(Bb * Nn / 64), dim3(256), 0, stream, nfB, Wfb, bf, out, XT);
    hipLaunchKernelGGL(k_node1_mfma, dim3(Bb * 4), dim3(256), 0, stream, DAf, XT, out);
}

// Round 6
// 300.018 us; speedup vs baseline: 1.2929x; 1.0435x over previous
//
#include <hip/hip_runtime.h>
#include <hip/hip_bf16.h>
#include <math.h>

#define Bb   64
#define Nn   256
#define Mm   16
#define ONF  92
#define OEF  41
#define NF   128
#define EF   64
#define KDIM 320   // 2*NF + EF
#define ODIM 256   // 2*NF
#define FINAL 128
#define K0C  6     // conv K-chunks (K=192: gather 128 + edge 64)

#define LOG2E_F 1.44269504088896f
#define LN2_F   0.6931471805599453f

typedef __attribute__((ext_vector_type(8))) short short8;
typedef __attribute__((ext_vector_type(4))) float f32x4;

#define AS1 __attribute__((address_space(1)))
#define AS3 __attribute__((address_space(3)))

// async global->LDS DMA, 16B per lane. LDS dest = wave-uniform base + lane*16;
// global source is per-lane. Drained by the vmcnt(0) implicit in __syncthreads().
__device__ __forceinline__ void gl2lds16(const void* gp, void* lp) {
    __builtin_amdgcn_global_load_lds((AS1 void*)(void*)gp, (AS3 void*)lp, 16, 0, 0);
}

__device__ __forceinline__ float sigmoidf_(float x) {
    float e = __expf(-x);
    return __builtin_amdgcn_rcpf(1.0f + e);
}
__device__ __forceinline__ float softplusf_(float x) {
    return fmaxf(x, 0.0f) + __logf(1.0f + __expf(-fabsf(x)));
}
__device__ __forceinline__ __hip_bfloat16 to_bf16(float x) { return __float2bfloat16(x); }

// ---------- mega-prep: all weight swizzles + WeT + DA in ONE launch ----------
__device__ __forceinline__ void swz(const float* __restrict__ in, __hip_bfloat16* __restrict__ out,
                                    int t, int Itot, int koff, int Kuse, int K0, float scale)
{
    int j = t & 7;
    int u = t >> 3;
    int lane = u & 63;
    int ln16 = lane & 15, q = lane >> 4;
    int v = u >> 6;
    int k0 = v % K0, tile = v / K0;
    int n = tile * 16 + ln16, k = k0 * 32 + q * 8 + j;
    out[t] = (k < Kuse) ? to_bf16(scale * in[(size_t)n * Itot + koff + k]) : to_bf16(0.0f);
}

#define SZ_WET (OEF * EF)          // 2624
#define SZ_WB  (16 * K0C * 512)    // 49152
#define SZ_WS  (16 * 4 * 512)      // 32768
#define SZ_WNB ((NF / 16) * 3 * 512)
#define SZ_WEB ((EF / 16) * 2 * 512)
#define SZ_WFB ((64 / 16) * 4 * 512)
#define SZ_DA  (Nn * Nn)
#define PREP_TOTAL (SZ_WET + 3 * SZ_WB + 3 * SZ_WS + SZ_WNB + SZ_WEB + SZ_WFB + SZ_DA)

__global__ __launch_bounds__(256) void k_prep(
    const float* __restrict__ We, const float* __restrict__ W1,
    const float* __restrict__ W2, const float* __restrict__ W3,
    const float* __restrict__ Wn, const float* __restrict__ Wf,
    const float* __restrict__ dis, const float* __restrict__ pw, const float* __restrict__ pb,
    float* __restrict__ WeT,
    __hip_bfloat16* __restrict__ W1b, __hip_bfloat16* __restrict__ W2b, __hip_bfloat16* __restrict__ W3b,
    __hip_bfloat16* __restrict__ W1s, __hip_bfloat16* __restrict__ W2s, __hip_bfloat16* __restrict__ W3s,
    __hip_bfloat16* __restrict__ Wnb, __hip_bfloat16* __restrict__ Web, __hip_bfloat16* __restrict__ Wfb,
    __hip_bfloat16* __restrict__ DAf)
{
    int t = blockIdx.x * 256 + threadIdx.x;
    if (t < SZ_WET) {
        int o = t / OEF, i = t - o * OEF;
        WeT[i * EF + o] = We[t];
        return;
    }
    t -= SZ_WET;
    if (t < SZ_WB) { swz(W1, W1b, t, KDIM, NF, 192, K0C, LOG2E_F); return; }
    t -= SZ_WB;
    if (t < SZ_WB) { swz(W2, W2b, t, KDIM, NF, 192, K0C, LOG2E_F); return; }
    t -= SZ_WB;
    if (t < SZ_WB) { swz(W3, W3b, t, KDIM, NF, 192, K0C, LOG2E_F); return; }
    t -= SZ_WB;
    if (t < SZ_WS) { swz(W1, W1s, t, KDIM, 0, NF, 4, LOG2E_F); return; }
    t -= SZ_WS;
    if (t < SZ_WS) { swz(W2, W2s, t, KDIM, 0, NF, 4, LOG2E_F); return; }
    t -= SZ_WS;
    if (t < SZ_WS) { swz(W3, W3s, t, KDIM, 0, NF, 4, LOG2E_F); return; }
    t -= SZ_WS;
    if (t < SZ_WNB) { swz(Wn, Wnb, t, ONF, 0, ONF, 3, 1.0f); return; }
    t -= SZ_WNB;
    if (t < SZ_WEB) { swz(We, Web, t, OEF, 0, OEF, 2, 1.0f); return; }
    t -= SZ_WEB;
    if (t < SZ_WFB) { swz(Wf, Wfb, t, NF, 0, NF, 4, 1.0f); return; }
    t -= SZ_WFB;
    if (t < SZ_DA) {
        int i = t >> 8, jx = t & 255;
        float v = sigmoidf_(fmaf(*pw, dis[t], *pb));
        int itile = i >> 4, ln16 = i & 15;
        int k0 = jx >> 5, q = (jx >> 3) & 3, jj = jx & 7;
        DAf[(size_t)((((itile * 8 + k0) << 6) + (q << 4) + ln16)) * 8 + jj] = to_bf16(v);
    }
}

// ---------- generic MFMA embed body ----------
template<int KIN, int K0, int NCOLS>
__device__ __forceinline__ void emb_body(
    int bid, const float* __restrict__ X, const __hip_bfloat16* __restrict__ Bswz,
    const float* __restrict__ bias, __hip_bfloat16* __restrict__ Y,
    __hip_bfloat16* A_s, __hip_bfloat16* O_s)
{
    constexpr int KP = K0 * 32;
    constexpr int TPW = NCOLS / 64;
    constexpr int OLD = NCOLS + 24;

    const int row0 = bid * 64;
    const int t = threadIdx.x;

    {
        const float4* Xb = (const float4*)(X + (size_t)row0 * KIN);
        constexpr int NV = (64 * KIN) / 4;
        for (int c = t; c < NV; c += 256) {
            float4 v = Xb[c];
            int flat = c * 4;
            #pragma unroll
            for (int e = 0; e < 4; e++) {
                int f = flat + e;
                int row = f / KIN, k = f - row * KIN;
                int mt = row >> 4, ln16 = row & 15;
                int k0 = k >> 5, q = (k >> 3) & 3, j = k & 7;
                float vv = (e == 0) ? v.x : (e == 1) ? v.y : (e == 2) ? v.z : v.w;
                A_s[(((mt * K0 + k0) << 6) + (q << 4) + ln16) * 8 + j] = to_bf16(vv);
            }
        }
        constexpr int PAD = KP - KIN;
        for (int c = t; c < 64 * PAD; c += 256) {
            int row = c / PAD, k = KIN + (c - row * PAD);
            int mt = row >> 4, ln16 = row & 15;
            int k0 = k >> 5, q = (k >> 3) & 3, j = k & 7;
            A_s[(((mt * K0 + k0) << 6) + (q << 4) + ln16) * 8 + j] = to_bf16(0.0f);
        }
    }
    __syncthreads();

    const int wv = t >> 6, lane = t & 63;
    const int q = lane >> 4, ln16 = lane & 15;

    f32x4 acc[4][TPW];
    #pragma unroll
    for (int p = 0; p < TPW; p++) {
        float bv = bias[(wv * TPW + p) * 16 + ln16];
        #pragma unroll
        for (int mt = 0; mt < 4; mt++) acc[mt][p] = (f32x4){bv, bv, bv, bv};
    }

    short8 bw[TPW][K0];
    #pragma unroll
    for (int p = 0; p < TPW; p++)
        #pragma unroll
        for (int k0 = 0; k0 < K0; k0++)
            bw[p][k0] = *(const short8*)(Bswz + ((size_t)((wv * TPW + p) * K0 + k0) << 9) + (lane << 3));

    #pragma unroll
    for (int k0 = 0; k0 < K0; k0++) {
        short8 af[4];
        #pragma unroll
        for (int mt = 0; mt < 4; mt++)
            af[mt] = *(const short8*)(A_s + (((mt * K0 + k0) << 6) + lane) * 8);
        #pragma unroll
        for (int mt = 0; mt < 4; mt++)
            #pragma unroll
            for (int p = 0; p < TPW; p++)
                acc[mt][p] = __builtin_amdgcn_mfma_f32_16x16x32_bf16(af[mt], bw[p][k0], acc[mt][p], 0, 0, 0);
    }

    #pragma unroll
    for (int mt = 0; mt < 4; mt++)
        #pragma unroll
        for (int p = 0; p < TPW; p++) {
            int col = (wv * TPW + p) * 16 + ln16;
            #pragma unroll
            for (int r = 0; r < 4; r++)
                O_s[(mt * 16 + q * 4 + r) * OLD + col] = to_bf16(acc[mt][p][r]);
        }
    __syncthreads();
    constexpr int CH = NCOLS / 8;
    for (int c = t; c < 64 * CH; c += 256) {
        int row = c / CH, ch = c - row * CH;
        *(uint4*)(Y + (size_t)(row0 + row) * NCOLS + ch * 8) =
            *(const uint4*)(O_s + row * OLD + ch * 8);
    }
}

// blocks [0,256): node embed; [256, 256+4096): edge embed
__global__ __launch_bounds__(256) void k_embed_all(
    const float* __restrict__ node_fea, const __hip_bfloat16* __restrict__ Wnb,
    const float* __restrict__ bn, __hip_bfloat16* __restrict__ nf0,
    const float* __restrict__ edge_fea, const __hip_bfloat16* __restrict__ Web,
    const float* __restrict__ be, __hip_bfloat16* __restrict__ efb)
{
    __shared__ __align__(16) __hip_bfloat16 A_s[4 * 3 * 512];
    __shared__ __align__(16) __hip_bfloat16 O_s[64 * (NF + 24)];
    if (blockIdx.x < 256)
        emb_body<ONF, 3, NF>(blockIdx.x, node_fea, Wnb, bn, nf0, A_s, O_s);
    else
        emb_body<OEF, 2, EF>(blockIdx.x - 256, edge_fea, Web, be, efb, A_s, O_s);
}

// ---------- S GEMM: S[n][o] = log2e*(nf[n] @ Wself[o] + bias[o]), f32 out ----------
__global__ __launch_bounds__(256) void k_gemm_s(
    const __hip_bfloat16* __restrict__ nf,
    const __hip_bfloat16* __restrict__ Ws,
    const float* __restrict__ bias,
    float* __restrict__ S)
{
    __shared__ __align__(16) __hip_bfloat16 A_s[16 * 512];
    const int row0 = blockIdx.x * 64;
    const int t = threadIdx.x;
    const int wv = t >> 6, lane = t & 63;
    const int q = lane >> 4, ln16 = lane & 15;

    #pragma unroll
    for (int k0 = 0; k0 < 4; k0++)
        gl2lds16(nf + (size_t)(row0 + (wv << 4) + ln16) * NF + k0 * 32 + q * 8,
                 A_s + ((wv * 4 + k0) * 64 + lane) * 8);
    __syncthreads();

    short8 bw[4][4];
    #pragma unroll
    for (int p = 0; p < 4; p++)
        #pragma unroll
        for (int k0 = 0; k0 < 4; k0++)
            bw[p][k0] = *(const short8*)(Ws + ((size_t)((wv * 4 + p) * 4 + k0) << 9) + (lane << 3));

    f32x4 acc[4][4];
    #pragma unroll
    for (int p = 0; p < 4; p++) {
        float bv = bias[(wv * 4 + p) * 16 + ln16] * LOG2E_F;
        #pragma unroll
        for (int mt = 0; mt < 4; mt++) acc[mt][p] = (f32x4){bv, bv, bv, bv};
    }

    #pragma unroll
    for (int k0 = 0; k0 < 4; k0++) {
        short8 af[4];
        #pragma unroll
        for (int mt = 0; mt < 4; mt++)
            af[mt] = *(const short8*)(A_s + ((mt * 4 + k0) * 64 + lane) * 8);
        #pragma unroll
        for (int mt = 0; mt < 4; mt++)
            #pragma unroll
            for (int p = 0; p < 4; p++)
                acc[mt][p] = __builtin_amdgcn_mfma_f32_16x16x32_bf16(af[mt], bw[p][k0], acc[mt][p], 0, 0, 0);
    }

    #pragma unroll
    for (int mt = 0; mt < 4; mt++)
        #pragma unroll
        for (int p = 0; p < 4; p++) {
            int col = (wv * 4 + p) * 16 + ln16;
            #pragma unroll
            for (int r = 0; r < 4; r++)
                S[(size_t)(row0 + mt * 16 + q * 4 + r) * ODIM + col] = acc[mt][p][r];
        }
}

// ---------- conv layer R6: weights in LDS, free-running waves ----------
// Grid 512 x 512 threads = exactly 2 blocks/CU (LDS 48KB each), 16 waves/CU.
// Block: cs = bid>>8 picks the column half (F cols cs*64..cs*64+63 and the
// matching C cols 128+...). bid & 255 picks 16 groups; each of the 8 waves
// owns 2 groups (g = gblk*16 + task*8 + wv) and runs with NO barriers after
// the one-time weight staging: A-fragments loaded directly from global
// (fragment layout = 16B/lane), weights via ds_read_b128, S/self hoisted.
// cs pairing (bid, bid+256) lands on the same XCD -> efb L2 reuse.
__global__ __launch_bounds__(512, 4) void k_conv_w(
    const __hip_bfloat16* __restrict__ nf_in,   // [B*N][NF] bf16
    const __hip_bfloat16* __restrict__ ef_bf,   // [B*N*M][EF] bf16
    const int*   __restrict__ eidx,             // [B*N][M]
    const __hip_bfloat16* __restrict__ Wb,      // [16][K0C][512] (log2e*W[:,128:320])
    const float* __restrict__ Sbuf,             // [B*N][ODIM] f32 = log2e*(self+bias)
    const float* __restrict__ palpha,
    __hip_bfloat16* __restrict__ nf_out)        // [B*N][NF] bf16
{
    __shared__ __align__(16) __hip_bfloat16 Wl[8 * K0C * 512];   // 48 KB

    const int t = threadIdx.x;
    const int wv = t >> 6, lane = t & 63;
    const int q = lane >> 4, ln16 = lane & 15;
    const int cs = blockIdx.x >> 8;              // column half 0/1
    const int gblk = blockIdx.x & 255;
    const float alpha = *palpha;

    // ---- stage this colset's 8 weight tiles: F tiles cs*4+0..3, C tiles 8+cs*4+0..3
    #pragma unroll
    for (int p = 0; p < 6; p++) {
        int idx = p * 512 + t;                   // 16B chunk id in [0, 3072)
        int tll = idx / 384;                     // local tile 0..7 (384 chunks/tile)
        int cin = idx - tll * 384;
        int gt  = (tll < 4) ? (cs * 4 + tll) : (8 + cs * 4 + (tll - 4));
        gl2lds16(Wb + (size_t)gt * (K0C * 512) + cin * 8, Wl + (size_t)idx * 8);
    }
    __syncthreads();   // the ONLY barrier; waves free-run below

    #pragma unroll 1
    for (int task = 0; task < 2; task++) {
        const int g = gblk * 16 + (task << 3) + wv;   // group of 4 nodes
        const int node0g = g * 4;
        const int bbase = node0g & ~255;
        const int jv = eidx[(node0g << 4) + lane];    // lane = edge index in group
        const unsigned long long mball = __ballot(jv >= 0);

        #pragma unroll 1
        for (int h = 0; h < 2; h++) {
            // ---- A-fragments for nodes 2h, 2h+1 direct from global (48 VGPR)
            short8 afr[2][K0C];
            #pragma unroll
            for (int mtl = 0; mtl < 2; mtl++) {
                const int mt = 2 * h + mtl;
                int jm = __shfl(jv, (mt << 4) + ln16);
                jm = jm < 0 ? 0 : jm;
                const __hip_bfloat16* gp = nf_in + (size_t)(bbase + jm) * NF + q * 8;
                #pragma unroll
                for (int k0 = 0; k0 < 4; k0++)
                    afr[mtl][k0] = *(const short8*)(gp + k0 * 32);
                const __hip_bfloat16* ep =
                    ef_bf + ((size_t)((node0g + mt) << 4) + ln16) * EF + q * 8;
                afr[mtl][4] = *(const short8*)(ep);
                afr[mtl][5] = *(const short8*)(ep + 32);
            }

            // ---- S / self prefetch for all 4 col-tiles of this colset (24 VGPR)
            float sF[2][4], sC[2][4], svv[2][4];
            #pragma unroll
            for (int mtl = 0; mtl < 2; mtl++) {
                const int gnode = node0g + 2 * h + mtl;
                const float* Sr = Sbuf + (size_t)gnode * ODIM + cs * 64 + ln16;
                const __hip_bfloat16* nr = nf_in + (size_t)gnode * NF + cs * 64 + ln16;
                #pragma unroll
                for (int c = 0; c < 4; c++) {
                    sF[mtl][c] = Sr[c * 16];
                    sC[mtl][c] = Sr[128 + c * 16];
                    svv[mtl][c] = __bfloat162float(nr[c * 16]);
                }
            }

            // ---- per col-tile: K-loop (LDS weights) + fused epilogue
            #pragma unroll 1
            for (int ctl = 0; ctl < 4; ctl++) {
                f32x4 accF[2], accC[2];
                #pragma unroll
                for (int mtl = 0; mtl < 2; mtl++) {
                    float vF = sF[mtl][ctl], vC = sC[mtl][ctl];
                    accF[mtl] = (f32x4){vF, vF, vF, vF};
                    accC[mtl] = (f32x4){vC, vC, vC, vC};
                }
                #pragma unroll
                for (int k0 = 0; k0 < K0C; k0++) {
                    short8 wF = *(const short8*)(Wl + (((ctl)     * K0C + k0) << 9) + (lane << 3));
                    short8 wC = *(const short8*)(Wl + (((4 + ctl) * K0C + k0) << 9) + (lane << 3));
                    #pragma unroll
                    for (int mtl = 0; mtl < 2; mtl++) {
                        accF[mtl] = __builtin_amdgcn_mfma_f32_16x16x32_bf16(afr[mtl][k0], wF, accF[mtl], 0, 0, 0);
                        accC[mtl] = __builtin_amdgcn_mfma_f32_16x16x32_bf16(afr[mtl][k0], wC, accC[mtl], 0, 0, 0);
                    }
                }
                // epilogue (log2-domain): rows of C are edges, col = cs*64+ctl*16+ln16
                #pragma unroll
                for (int mtl = 0; mtl < 2; mtl++) {
                    const int mt = 2 * h + mtl;
                    const int gnode = node0g + mt;
                    unsigned mbits = (unsigned)(mball >> ((mt << 4) + (q << 2))) & 0xFu;
                    float partial = 0.0f;
                    #pragma unroll
                    for (int r = 0; r < 4; r++) {
                        bool msk = (mbits >> r) & 1u;
                        float f2 = accF[mtl][r];
                        float c2 = accC[mtl][r];
                        float sig = __builtin_amdgcn_rcpf(1.0f + __builtin_amdgcn_exp2f(-f2));
                        float sp2 = fmaxf(c2, 0.0f) +
                                    __builtin_amdgcn_logf(1.0f + __builtin_amdgcn_exp2f(-fabsf(c2)));
                        partial += msk ? sig * sp2 : 0.0f;
                    }
                    partial += __shfl_xor(partial, 16);
                    partial += __shfl_xor(partial, 32);
                    if (q == 0) {
                        int col = cs * 64 + ctl * 16 + ln16;
                        nf_out[(size_t)gnode * NF + col] =
                            to_bf16(softplusf_(fmaf(alpha, svv[mtl][ctl], LN2_F * partial)));
                    }
                }
            }
        }
    }
}

// ---------- fallback conv layer (non-precomp path; unchanged) ----------
template<bool PRECOMP>
__global__ __launch_bounds__(256, 3) void k_conv_mfma(
    const __hip_bfloat16* __restrict__ nf_in,
    const float* __restrict__ edge_fea,
    const __hip_bfloat16* __restrict__ ef_bf,
    const int*   __restrict__ eidx,
    const float* __restrict__ WeT,
    const float* __restrict__ be,
    const __hip_bfloat16* __restrict__ Wb,
    const __hip_bfloat16* __restrict__ Wsb,
    const float* __restrict__ bias,
    const float* __restrict__ palpha,
    __hip_bfloat16* __restrict__ nf_out)
{
    __shared__ __align__(16) __hip_bfloat16 A_s[4 * K0C * 512];
    __shared__ __align__(16) __hip_bfloat16 A_sf[4 * 512];

    const int node0 = blockIdx.x * 4;
    const int b = node0 >> 8;
    const int t = threadIdx.x;
    const int wv = t >> 6, lane = t & 63;
    const int q = lane >> 4, ln16 = lane & 15;
    const int row = (wv << 4) + ln16;

    const int myidx = eidx[node0 * Mm + row];
    const unsigned long long mball = __ballot(eidx[node0 * Mm + lane] >= 0);

    float selfv[8];
    #pragma unroll
    for (int mt = 0; mt < 4; mt++)
        #pragma unroll
        for (int p = 0; p < 2; p++)
            selfv[mt * 2 + p] =
                __bfloat162float(nf_in[(size_t)(node0 + mt) * NF + (2 * wv + p) * 16 + ln16]);

    {
        int j = myidx < 0 ? 0 : myidx;
        const __hip_bfloat16* gathp = nf_in + (size_t)((b << 8) + j) * NF;
        #pragma unroll
        for (int k0 = 0; k0 < 4; k0++)
            *(uint4*)(A_s + ((wv * K0C + k0) * 64 + lane) * 8) =
                *(const uint4*)(gathp + k0 * 32 + q * 8);
        *(uint4*)(A_sf + (wv * 64 + lane) * 8) =
            *(const uint4*)(nf_in + (size_t)(node0 + (ln16 & 3)) * NF + wv * 32 + q * 8);
        if (PRECOMP) {
            const __hip_bfloat16* efp = ef_bf + (size_t)((node0 << 4) + row) * EF;
            #pragma unroll
            for (int k0 = 0; k0 < 2; k0++)
                *(uint4*)(A_s + ((wv * K0C + 4 + k0) * 64 + lane) * 8) =
                    *(const uint4*)(efp + k0 * 32 + q * 8);
        } else {
            for (int c = t; c < 64 * EF; c += 256) {
                int rr = c >> 6, col = c & 63;
                float a = be[col];
                const float* er = edge_fea + (size_t)(node0 * Mm + rr) * OEF;
                #pragma unroll
                for (int i = 0; i < OEF; i++) a = fmaf(er[i], WeT[i * EF + col], a);
                int mt = rr >> 4, l16 = rr & 15;
                int k0 = 4 + (col >> 5), qq = (col >> 3) & 3, jj = col & 7;
                A_s[((mt * K0C + k0) * 64 + qq * 16 + l16) * 8 + jj] = to_bf16(a);
            }
        }
    }
    __syncthreads();

    f32x4 sv[4];
    #pragma unroll
    for (int c = 0; c < 4; c++) {
        int tile = 2 * wv + (c & 1) + ((c >> 1) << 3);
        float bv = bias[tile * 16 + ln16] * LOG2E_F;
        sv[c] = (f32x4){bv, bv, bv, bv};
    }
    #pragma unroll
    for (int k0 = 0; k0 < 4; k0++) {
        short8 afs = *(const short8*)(A_sf + (k0 * 64 + lane) * 8);
        #pragma unroll
        for (int c = 0; c < 4; c++) {
            int tile = 2 * wv + (c & 1) + ((c >> 1) << 3);
            short8 bws = *(const short8*)(Wsb + ((size_t)(tile * 4 + k0) << 9) + (lane << 3));
            sv[c] = __builtin_amdgcn_mfma_f32_16x16x32_bf16(afs, bws, sv[c], 0, 0, 0);
        }
    }

    f32x4 accF[4][2], accC[4][2];
    #pragma unroll
    for (int mt = 0; mt < 4; mt++) {
        #pragma unroll
        for (int p = 0; p < 2; p++) {
            float vF = __shfl(sv[p][mt], ln16);
            float vC = __shfl(sv[2 + p][mt], ln16);
            accF[mt][p] = (f32x4){vF, vF, vF, vF};
            accC[mt][p] = (f32x4){vC, vC, vC, vC};
        }
    }

    const __hip_bfloat16* WF0 = Wb + ((size_t)(2 * wv) * (K0C * 512)) + (lane << 3);
    const __hip_bfloat16* WF1 = WF0 + K0C * 512;
    const __hip_bfloat16* WC0 = WF0 + 8 * (K0C * 512);
    const __hip_bfloat16* WC1 = WC0 + K0C * 512;

    #pragma unroll
    for (int k0 = 0; k0 < K0C; k0++) {
        short8 cF0 = *(const short8*)(WF0 + k0 * 512);
        short8 cF1 = *(const short8*)(WF1 + k0 * 512);
        short8 cC0 = *(const short8*)(WC0 + k0 * 512);
        short8 cC1 = *(const short8*)(WC1 + k0 * 512);
        short8 af[4];
        #pragma unroll
        for (int mt = 0; mt < 4; mt++)
            af[mt] = *(const short8*)(A_s + ((mt * K0C + k0) * 64 + lane) * 8);
        #pragma unroll
        for (int mt = 0; mt < 4; mt++) {
            accF[mt][0] = __builtin_amdgcn_mfma_f32_16x16x32_bf16(af[mt], cF0, accF[mt][0], 0, 0, 0);
            accF[mt][1] = __builtin_amdgcn_mfma_f32_16x16x32_bf16(af[mt], cF1, accF[mt][1], 0, 0, 0);
            accC[mt][0] = __builtin_amdgcn_mfma_f32_16x16x32_bf16(af[mt], cC0, accC[mt][0], 0, 0, 0);
            accC[mt][1] = __builtin_amdgcn_mfma_f32_16x16x32_bf16(af[mt], cC1, accC[mt][1], 0, 0, 0);
        }
    }

    const float alpha = *palpha;
    #pragma unroll
    for (int mt = 0; mt < 4; mt++) {
        const int gnode = node0 + mt;
        unsigned mbits = (unsigned)(mball >> (mt * 16 + q * 4)) & 0xFu;
        #pragma unroll
        for (int p = 0; p < 2; p++) {
            float partial = 0.0f;
            #pragma unroll
            for (int r = 0; r < 4; r++) {
                bool msk = (mbits >> r) & 1u;
                float f2 = accF[mt][p][r];
                float c2 = accC[mt][p][r];
                float sig = __builtin_amdgcn_rcpf(1.0f + __builtin_amdgcn_exp2f(-f2));
                float sp2 = fmaxf(c2, 0.0f) +
                            __builtin_amdgcn_logf(1.0f + __builtin_amdgcn_exp2f(-fabsf(c2)));
                partial += msk ? sig * sp2 : 0.0f;
            }
            partial += __shfl_xor(partial, 16);
            partial += __shfl_xor(partial, 32);
            if (q == 0) {
                int col = (2 * wv + p) * 16 + ln16;
                nf_out[(size_t)gnode * NF + col] =
                    to_bf16(softplusf_(fmaf(alpha, selfv[mt * 2 + p], LN2_F * partial)));
            }
        }
    }
}

// ---------- final linear (MFMA): out[:, :, 0:64] = nf3 @ Wf^T + bf ----------
__global__ __launch_bounds__(256) void k_final_mfma(
    const __hip_bfloat16* __restrict__ nf, const __hip_bfloat16* __restrict__ Wfb,
    const float* __restrict__ bfv, float* __restrict__ out,
    __hip_bfloat16* __restrict__ XT)
{
    __shared__ __align__(16) __hip_bfloat16 A_s[16 * 512];
    const int node0 = blockIdx.x * 64;
    const int bloc = node0 >> 8;
    const int t = threadIdx.x;
    const int wv = t >> 6, lane = t & 63;
    const int q = lane >> 4, ln16 = lane & 15;

    const __hip_bfloat16* rowp = nf + (size_t)(node0 + (wv << 4) + ln16) * NF;
    #pragma unroll
    for (int k0 = 0; k0 < 4; k0++)
        *(uint4*)(A_s + ((wv * 4 + k0) * 64 + lane) * 8) =
            *(const uint4*)(rowp + k0 * 32 + q * 8);
    __syncthreads();

    short8 bw[4];
    #pragma unroll
    for (int k0 = 0; k0 < 4; k0++)
        bw[k0] = *(const short8*)(Wfb + ((size_t)(wv * 4 + k0) * 64 + lane) * 8);

    float bv = bfv[wv * 16 + ln16];
    f32x4 acc[4];
    #pragma unroll
    for (int mt = 0; mt < 4; mt++) acc[mt] = (f32x4){bv, bv, bv, bv};

    #pragma unroll
    for (int k0 = 0; k0 < 4; k0++) {
        short8 af[4];
        #pragma unroll
        for (int mt = 0; mt < 4; mt++)
            af[mt] = *(const short8*)(A_s + ((mt * 4 + k0) * 64 + lane) * 8);
        #pragma unroll
        for (int mt = 0; mt < 4; mt++)
            acc[mt] = __builtin_amdgcn_mfma_f32_16x16x32_bf16(af[mt], bw[k0], acc[mt], 0, 0, 0);
    }

    const int col = (wv << 4) + ln16;
    #pragma unroll
    for (int mt = 0; mt < 4; mt++)
        #pragma unroll
        for (int r = 0; r < 4; r++) {
            int row = mt * 16 + q * 4 + r;
            float v = acc[mt][r];
            out[(size_t)(node0 + row) * FINAL + col] = v;
            XT[(size_t)(bloc * 64 + col) * 256 + (node0 & 255) + row] = to_bf16(v);
        }
}

// ---------- node1 (MFMA): out[:, :, 64:128] = DA @ nff per batch ----------
__global__ __launch_bounds__(256) void k_node1_mfma(
    const __hip_bfloat16* __restrict__ DAf,
    const __hip_bfloat16* __restrict__ XT,
    float* __restrict__ out)
{
    __shared__ __align__(16) __hip_bfloat16 B_s[32 * 512];
    const int blk = blockIdx.x;
    const int b = blk >> 2, i0 = (blk & 3) * 64;
    const int t = threadIdx.x;
    const int wv = t >> 6, lane = t & 63;
    const int q = lane >> 4, ln16 = lane & 15;

    const __hip_bfloat16* xrow = XT + (size_t)(b * 64 + (wv << 4) + ln16) * 256;
    #pragma unroll
    for (int k0 = 0; k0 < 8; k0++)
        *(uint4*)(B_s + ((wv * 8 + k0) * 64 + lane) * 8) =
            *(const uint4*)(xrow + k0 * 32 + q * 8);
    __syncthreads();

    f32x4 acc[4];
    #pragma unroll
    for (int mt = 0; mt < 4; mt++) acc[mt] = (f32x4){0.f, 0.f, 0.f, 0.f};

    #pragma unroll
    for (int k0 = 0; k0 < 8; k0++) {
        short8 bfr = *(const short8*)(B_s + ((wv * 8 + k0) * 64 + lane) * 8);
        short8 af[4];
        #pragma unroll
        for (int mt = 0; mt < 4; mt++)
            af[mt] = *(const short8*)(DAf + (size_t)(((i0 >> 4) + mt) * 8 + k0) * 512 + (lane << 3));
        #pragma unroll
        for (int mt = 0; mt < 4; mt++)
            acc[mt] = __builtin_amdgcn_mfma_f32_16x16x32_bf16(af[mt], bfr, acc[mt], 0, 0, 0);
    }

    #pragma unroll
    for (int mt = 0; mt < 4; mt++)
        #pragma unroll
        for (int r = 0; r < 4; r++) {
            int i = i0 + mt * 16 + q * 4 + r;
            out[(size_t)((b << 8) + i) * FINAL + 64 + (wv << 4) + ln16] = acc[mt][r];
        }
}

extern "C" void kernel_launch(void* const* d_in, const int* in_sizes, int n_in,
                              void* d_out, int out_size, void* d_ws, size_t ws_size,
                              hipStream_t stream)
{
    const float* node_fea = (const float*)d_in[0];
    const float* edge_fea = (const float*)d_in[1];
    const int*   eidx     = (const int*)  d_in[2];
    const float* dis      = (const float*)d_in[3];
    const float* Wn = (const float*)d_in[4];
    const float* bn = (const float*)d_in[5];
    const float* We = (const float*)d_in[6];
    const float* be = (const float*)d_in[7];
    const float* W1 = (const float*)d_in[8];
    const float* b1 = (const float*)d_in[9];
    const float* a1 = (const float*)d_in[10];
    const float* W2 = (const float*)d_in[11];
    const float* b2 = (const float*)d_in[12];
    const float* a2 = (const float*)d_in[13];
    const float* W3 = (const float*)d_in[14];
    const float* b3 = (const float*)d_in[15];
    const float* a3 = (const float*)d_in[16];
    const float* Wf = (const float*)d_in[17];
    const float* bf = (const float*)d_in[18];
    const float* DAw = (const float*)d_in[19];
    const float* DAb = (const float*)d_in[20];
    float* out = (float*)d_out;

    // workspace layout (bytes, 256-aligned blocks)
    char* base = (char*)d_ws;
    size_t off = 0;
    auto alloc = [&](size_t bytes) { char* p = base + off; off = (off + bytes + 255) & ~(size_t)255; return p; };
    __hip_bfloat16* nfA = (__hip_bfloat16*)alloc((size_t)Bb * Nn * NF * 2);
    __hip_bfloat16* nfB = (__hip_bfloat16*)alloc((size_t)Bb * Nn * NF * 2);
    __hip_bfloat16* W1b = (__hip_bfloat16*)alloc((size_t)SZ_WB * 2);
    __hip_bfloat16* W2b = (__hip_bfloat16*)alloc((size_t)SZ_WB * 2);
    __hip_bfloat16* W3b = (__hip_bfloat16*)alloc((size_t)SZ_WB * 2);
    __hip_bfloat16* W1s = (__hip_bfloat16*)alloc((size_t)SZ_WS * 2);
    __hip_bfloat16* W2s = (__hip_bfloat16*)alloc((size_t)SZ_WS * 2);
    __hip_bfloat16* W3s = (__hip_bfloat16*)alloc((size_t)SZ_WS * 2);
    float* WeT = (float*)alloc((size_t)OEF * EF * 4);
    __hip_bfloat16* DAf = (__hip_bfloat16*)alloc((size_t)Nn * Nn * 2);
    __hip_bfloat16* Wnb = (__hip_bfloat16*)alloc((size_t)SZ_WNB * 2);
    __hip_bfloat16* Web = (__hip_bfloat16*)alloc((size_t)SZ_WEB * 2);
    __hip_bfloat16* Wfb = (__hip_bfloat16*)alloc((size_t)SZ_WFB * 2);
    __hip_bfloat16* XT  = (__hip_bfloat16*)alloc((size_t)Bb * 64 * Nn * 2);
    __hip_bfloat16* efb = (__hip_bfloat16*)alloc((size_t)Bb * Nn * Mm * EF * 2);    // 33.5 MB
    float* Sbuf = (float*)alloc((size_t)Bb * Nn * ODIM * 4);                        // 16.8 MB
    const bool precomp = (ws_size >= off);

    hipLaunchKernelGGL(k_prep, dim3((PREP_TOTAL + 255) / 256), dim3(256), 0, stream,
                       We, W1, W2, W3, Wn, Wf, dis, DAw, DAb,
                       WeT, W1b, W2b, W3b, W1s, W2s, W3s, Wnb, Web, Wfb, DAf);

    hipLaunchKernelGGL(k_embed_all, dim3(precomp ? (256 + Bb * Nn * Mm / 64) : 256), dim3(256), 0, stream,
                       node_fea, Wnb, bn, nfA, edge_fea, Web, be, efb);

    if (precomp) {
        hipLaunchKernelGGL(k_gemm_s, dim3(Bb * Nn / 64), dim3(256), 0, stream,
                           nfA, W1s, b1, Sbuf);
        hipLaunchKernelGGL(k_conv_w, dim3(512), dim3(512), 0, stream,
                           nfA, efb, eidx, W1b, Sbuf, a1, nfB);
        hipLaunchKernelGGL(k_gemm_s, dim3(Bb * Nn / 64), dim3(256), 0, stream,
                           nfB, W2s, b2, Sbuf);
        hipLaunchKernelGGL(k_conv_w, dim3(512), dim3(512), 0, stream,
                           nfB, efb, eidx, W2b, Sbuf, a2, nfA);
        hipLaunchKernelGGL(k_gemm_s, dim3(Bb * Nn / 64), dim3(256), 0, stream,
                           nfA, W3s, b3, Sbuf);
        hipLaunchKernelGGL(k_conv_w, dim3(512), dim3(512), 0, stream,
                           nfA, efb, eidx, W3b, Sbuf, a3, nfB);
    } else {
        hipLaunchKernelGGL((k_conv_mfma<false>), dim3(Bb * Nn / 4), dim3(256), 0, stream,
                           nfA, edge_fea, efb, eidx, WeT, be, W1b, W1s, b1, a1, nfB);
        hipLaunchKernelGGL((k_conv_mfma<false>), dim3(Bb * Nn / 4), dim3(256), 0, stream,
                           nfB, edge_fea, efb, eidx, WeT, be, W2b, W2s, b2, a2, nfA);
        hipLaunchKernelGGL((k_conv_mfma<false>), dim3(Bb * Nn / 4), dim3(256), 0, stream,
                           nfA, edge_fea, efb, eidx, WeT, be, W3b, W3s, b3, a3, nfB);
    }

    hipLaunchKernelGGL(k_final_mfma, dim3(Bb * Nn / 64), dim3(256), 0, stream, nfB, Wfb, bf, out, XT);
    hipLaunchKernelGGL(k_node1_mfma, dim3(Bb * 4), dim3(256), 0, stream, DAf, XT, out);
}